// Round 1
// baseline (308.985 us; speedup 1.0000x reference)
//
#include <hip/hip_runtime.h>
#include <hip/hip_bf16.h>

#define B_ 2
#define N_ 2048
#define HID_ 256
#define HEADS_ 4
#define D_ 64
#define POOL_ 128

typedef __bf16 bf16;
typedef __bf16 bf16x8 __attribute__((ext_vector_type(8)));
typedef float f32x4 __attribute__((ext_vector_type(4)));

// ---------------- input projection: x = relu(ge*w+b), plus bf16 copy ----------------
__global__ void k_input_proj(const float* __restrict__ ge, const float* __restrict__ w,
                             const float* __restrict__ b, float* __restrict__ x,
                             bf16* __restrict__ xb) {
    int row = blockIdx.x;            // B*N
    int c = threadIdx.x;             // HID
    float g = ge[row];
    float v = fmaxf(g * w[c] + b[c], 0.f);
    x[row * HID_ + c] = v;
    xb[row * HID_ + c] = (bf16)v;
}

// ---------------- adjacency -> bitmask [B][N][N/32] u32 ----------------
__global__ void k_adjbits(const int* __restrict__ adj, unsigned* __restrict__ am) {
    int o = blockIdx.x * blockDim.x + threadIdx.x;   // B*N*64
    const int* p = adj + (long long)o * 32;
    unsigned bits = 0;
    #pragma unroll
    for (int t = 0; t < 32; ++t) bits |= (p[t] > 0 ? 1u : 0u) << t;
    am[o] = bits;
}

// ---------------- transpose f32 [K][Nc] -> bf16 [Nc][K] ----------------
__global__ void k_transpose_bf16(const float* __restrict__ in, bf16* __restrict__ out,
                                 int K, int Nc) {
    int o = blockIdx.x * blockDim.x + threadIdx.x;   // Nc*K
    int n = o / K, k = o % K;
    out[o] = (bf16)in[k * Nc + n];
}

// ---------------- generic MFMA GEMM: C[M][NC] = A[M][256] * BT[NC][256]^T ----------------
__global__ __launch_bounds__(256) void k_gemm(const bf16* __restrict__ A,
                                              const bf16* __restrict__ BT,
                                              float* __restrict__ C, int NC) {
    int i0 = blockIdx.x * 64, n0 = blockIdx.y * 64;
    int w = threadIdx.x >> 6, lane = threadIdx.x & 63, r = lane & 15, g = lane >> 4;
    const bf16* ap = A + (i0 + w * 16 + r) * 256 + g * 8;
    f32x4 acc[4] = {{0,0,0,0},{0,0,0,0},{0,0,0,0},{0,0,0,0}};
    for (int ks = 0; ks < 256; ks += 32) {
        bf16x8 af = *(const bf16x8*)(ap + ks);
        #pragma unroll
        for (int nf = 0; nf < 4; ++nf) {
            bf16x8 bfr = *(const bf16x8*)(BT + (n0 + nf * 16 + r) * 256 + ks + g * 8);
            acc[nf] = __builtin_amdgcn_mfma_f32_16x16x32_bf16(af, bfr, acc[nf], 0, 0, 0);
        }
    }
    #pragma unroll
    for (int q = 0; q < 4; ++q) {
        int row = i0 + w * 16 + g * 4 + q;
        #pragma unroll
        for (int nf = 0; nf < 4; ++nf) {
            int col = n0 + nf * 16 + r;
            C[row * NC + col] = acc[nf][q];
        }
    }
}

// ---------------- GEMM for h = x @ W, writing h f32 and transposed bf16 hbT[B][H][D][N] ----------------
__global__ __launch_bounds__(256) void k_gemm_h(const bf16* __restrict__ A,
                                                const bf16* __restrict__ WT,
                                                float* __restrict__ h,
                                                bf16* __restrict__ hbT) {
    int i0 = blockIdx.x * 64, head = blockIdx.y;
    int n0 = head * 64;
    int w = threadIdx.x >> 6, lane = threadIdx.x & 63, r = lane & 15, g = lane >> 4;
    const bf16* ap = A + (i0 + w * 16 + r) * 256 + g * 8;
    f32x4 acc[4] = {{0,0,0,0},{0,0,0,0},{0,0,0,0},{0,0,0,0}};
    for (int ks = 0; ks < 256; ks += 32) {
        bf16x8 af = *(const bf16x8*)(ap + ks);
        #pragma unroll
        for (int nf = 0; nf < 4; ++nf) {
            bf16x8 bfr = *(const bf16x8*)(WT + (n0 + nf * 16 + r) * 256 + ks + g * 8);
            acc[nf] = __builtin_amdgcn_mfma_f32_16x16x32_bf16(af, bfr, acc[nf], 0, 0, 0);
        }
    }
    #pragma unroll
    for (int q = 0; q < 4; ++q) {
        int row = i0 + w * 16 + g * 4 + q;
        int b = row >> 11, nn = row & 2047;
        #pragma unroll
        for (int nf = 0; nf < 4; ++nf) {
            int dh = nf * 16 + r;
            float v = acc[nf][q];
            h[row * HID_ + n0 + dh] = v;
            hbT[(((b * HEADS_ + head) * D_) + dh) * N_ + nn] = (bf16)v;
        }
    }
}

// ---------------- src/dst projections: srcM/dstT [B][H][N] ----------------
__global__ void k_srcdst(const float* __restrict__ h, const float* __restrict__ as,
                         const float* __restrict__ ad, float* __restrict__ srcM,
                         float* __restrict__ dstT) {
    int gid = blockIdx.x * blockDim.x + threadIdx.x;  // B*H*N
    int b = gid >> 13, hd = (gid >> 11) & 3, n = gid & 2047;
    const float* hp = h + (b * N_ + n) * HID_ + hd * D_;
    float ss = 0.f, dd = 0.f;
    #pragma unroll 8
    for (int d = 0; d < D_; ++d) {
        float hv = hp[d];
        ss += hv * as[hd * D_ + d];
        dd += hv * ad[hd * D_ + d];
    }
    srcM[gid] = ss;
    dstT[gid] = dd;
}

// ---------------- per-(b,h) max over dst ----------------
__global__ void k_dmax(const float* __restrict__ dstT, float* __restrict__ dmax) {
    int rowid = blockIdx.x;   // B*H
    const float* p = dstT + rowid * N_;
    float m = -3e38f;
    for (int n = threadIdx.x; n < N_; n += 256) m = fmaxf(m, p[n]);
    #pragma unroll
    for (int o = 1; o < 64; o <<= 1) m = fmaxf(m, __shfl_xor(m, o));
    __shared__ float red[4];
    if ((threadIdx.x & 63) == 0) red[threadIdx.x >> 6] = m;
    __syncthreads();
    if (threadIdx.x == 0)
        dmax[rowid] = fmaxf(fmaxf(red[0], red[1]), fmaxf(red[2], red[3]));
}

// ---------------- fused GAT attention: P built in registers, PV via MFMA ----------------
__global__ __launch_bounds__(256) void k_attn(const float* __restrict__ srcM,
                                              const float* __restrict__ dstT,
                                              const float* __restrict__ dmaxp,
                                              const unsigned* __restrict__ am,
                                              const bf16* __restrict__ hbT,
                                              float* __restrict__ nodeOut,
                                              bf16* __restrict__ xbNext) {
    int it = blockIdx.x, hd = blockIdx.y, b = blockIdx.z;
    int i0 = it * 64;
    int w = threadIdx.x >> 6, lane = threadIdx.x & 63, r = lane & 15, g = lane >> 4;
    int i = i0 + w * 16 + r;
    int bh = b * HEADS_ + hd;
    float sv = srcM[bh * N_ + i];
    float dm = dmaxp[bh];
    float t0 = sv + dm;
    float mi = fmaxf(t0, 0.2f * t0);   // leaky(src_i + dmax) >= row max of leaky scores
    const float* drow = dstT + bh * N_;
    const unsigned* mrow = am + (b * N_ + i) * 64;
    const bf16* vbase = hbT + (long long)bh * D_ * N_;

    f32x4 acc[4] = {{0,0,0,0},{0,0,0,0},{0,0,0,0},{0,0,0,0}};
    float l = 0.f;

    for (int js = 0; js < N_; js += 32) {
        int jb = js + g * 8;
        float4 dv0 = *(const float4*)(drow + jb);
        float4 dv1 = *(const float4*)(drow + jb + 4);
        unsigned mb = (mrow[js >> 5] >> (g * 8)) & 0xFFu;
        float dd[8] = {dv0.x, dv0.y, dv0.z, dv0.w, dv1.x, dv1.y, dv1.z, dv1.w};
        bf16x8 af;
        float ls = 0.f;
        #pragma unroll
        for (int t = 0; t < 8; ++t) {
            float tt = sv + dd[t];
            float lv = fmaxf(tt, 0.2f * tt);      // leaky_relu(0.2)
            float e2 = __expf(lv - mi);
            e2 = ((mb >> t) & 1u) ? e2 : 0.f;
            ls += e2;
            af[t] = (bf16)e2;
        }
        l += ls;
        #pragma unroll
        for (int nf = 0; nf < 4; ++nf) {
            bf16x8 vf = *(const bf16x8*)(vbase + (nf * 16 + r) * N_ + jb);
            acc[nf] = __builtin_amdgcn_mfma_f32_16x16x32_bf16(af, vf, acc[nf], 0, 0, 0);
        }
    }
    // full row sums: combine the 4 g-groups (disjoint j ranges)
    l += __shfl_xor(l, 16);
    l += __shfl_xor(l, 32);
    __shared__ float lred[4][16];
    if (g == 0) lred[w][r] = l;
    __syncthreads();

    #pragma unroll
    for (int q = 0; q < 4; ++q) {
        float li = 1.f / lred[w][g * 4 + q];
        int n = i0 + w * 16 + g * 4 + q;
        #pragma unroll
        for (int nf = 0; nf < 4; ++nf) {
            float v = acc[nf][q] * li;
            float o = v > 0.f ? v : expm1f(v);   // elu
            int col = hd * D_ + nf * 16 + r;
            int idx = (b * N_ + n) * HID_ + col;
            nodeOut[idx] = o;
            xbNext[idx] = (bf16)o;
        }
    }
}

// ---------------- pool score part 2: s = sum tanh(t+b1)*w2 + b2 ----------------
__global__ void k_pool_sc(const float* __restrict__ t, const float* __restrict__ b1,
                          const float* __restrict__ w2, const float* __restrict__ b2p,
                          float* __restrict__ s) {
    int row = blockIdx.x * blockDim.x + threadIdx.x;  // B*N
    const float* tp = t + row * POOL_;
    float acc = 0.f;
    #pragma unroll 4
    for (int p = 0; p < POOL_; ++p) acc += tanhf(tp[p] + b1[p]) * w2[p];
    s[row] = acc + b2p[0];
}

// ---------------- pool softmax + weighted sum ----------------
__global__ __launch_bounds__(1024) void k_pool_reduce(const float* __restrict__ xsrc,
                                                      const float* __restrict__ s,
                                                      float* __restrict__ out) {
    __shared__ float e[N_];
    __shared__ float red[17];
    __shared__ float part[4][HID_];
    int b = blockIdx.x, tid = threadIdx.x;
    int lane = tid & 63, wid = tid >> 6;
    float v0 = s[b * N_ + tid], v1 = s[b * N_ + tid + 1024];
    float m = fmaxf(v0, v1);
    #pragma unroll
    for (int o = 1; o < 64; o <<= 1) m = fmaxf(m, __shfl_xor(m, o));
    if (lane == 0) red[wid] = m;
    __syncthreads();
    if (tid == 0) {
        float mm = red[0];
        for (int k2 = 1; k2 < 16; ++k2) mm = fmaxf(mm, red[k2]);
        red[16] = mm;
    }
    __syncthreads();
    m = red[16];
    float e0 = __expf(v0 - m), e1 = __expf(v1 - m);
    e[tid] = e0;
    e[tid + 1024] = e1;
    float z = e0 + e1;
    #pragma unroll
    for (int o = 1; o < 64; o <<= 1) z += __shfl_xor(z, o);
    __syncthreads();
    if (lane == 0) red[wid] = z;
    __syncthreads();
    if (tid == 0) {
        float zz = 0.f;
        for (int k2 = 0; k2 < 16; ++k2) zz += red[k2];
        red[16] = zz;
    }
    __syncthreads();
    float Z = red[16];
    int c = tid & 255, sl = tid >> 8;
    float acc = 0.f;
    const float* xp = xsrc + (b * N_ + sl * 512) * HID_ + c;
    for (int n = 0; n < 512; ++n) acc += e[sl * 512 + n] * xp[n * HID_];
    part[sl][c] = acc;
    __syncthreads();
    if (sl == 0)
        out[b * HID_ + c] = (part[0][c] + part[1][c] + part[2][c] + part[3][c]) / Z;
}

extern "C" void kernel_launch(void* const* d_in, const int* in_sizes, int n_in,
                              void* d_out, int out_size, void* d_ws, size_t ws_size,
                              hipStream_t stream) {
    const float* ge     = (const float*)d_in[0];
    const int*   adj    = (const int*)d_in[1];
    const float* in_w   = (const float*)d_in[2];
    const float* in_b   = (const float*)d_in[3];
    const float* proj_w = (const float*)d_in[4];
    const float* a_src  = (const float*)d_in[5];
    const float* a_dst  = (const float*)d_in[6];
    const float* pw1    = (const float*)d_in[7];
    const float* pb1    = (const float*)d_in[8];
    const float* pw2    = (const float*)d_in[9];
    const float* pb2    = (const float*)d_in[10];
    const float* ipw1   = (const float*)d_in[11];
    const float* ipb1   = (const float*)d_in[12];
    const float* ipw2   = (const float*)d_in[13];
    const float* ipb2   = (const float*)d_in[14];

    char* ws = (char*)d_ws;
    float*    x     = (float*)(ws + 0);            // 4 MB
    bf16*     xb    = (bf16*)(ws + 4194304);       // 2 MB
    float*    h     = (float*)(ws + 6291456);      // 4 MB
    bf16*     hbT   = (bf16*)(ws + 10485760);      // 2 MB
    float*    tp    = (float*)(ws + 12582912);     // 2 MB
    float*    sp    = (float*)(ws + 14680064);     // 16 KB
    float*    srcM  = (float*)(ws + 14696448);     // 64 KB
    float*    dstT  = (float*)(ws + 14761984);     // 64 KB
    float*    dmaxp = (float*)(ws + 14827520);     // 1 KB
    unsigned* am    = (unsigned*)(ws + 14828544);  // 1 MB
    bf16*     wT0   = (bf16*)(ws + 15877120);      // 128 KB
    bf16*     wT1   = wT0 + 65536;                 // 128 KB
    bf16*     ipw1T = wT1 + 65536;                 // 64 KB
    bf16*     w1T0  = ipw1T + 32768;               // 64 KB
    bf16*     w1T1  = w1T0 + 32768;                // 64 KB

    float* outRaw = (float*)d_out;
    float* node0  = outRaw + 512;
    float* node1  = node0 + 1048576;
    float* pool0  = node1 + 1048576;
    float* pool1  = pool0 + 512;

    k_input_proj<<<B_ * N_, HID_, 0, stream>>>(ge, in_w, in_b, x, xb);
    k_adjbits<<<1024, 256, 0, stream>>>(adj, am);
    k_transpose_bf16<<<256, 256, 0, stream>>>(proj_w, wT0, 256, 256);
    k_transpose_bf16<<<256, 256, 0, stream>>>(proj_w + 65536, wT1, 256, 256);
    k_transpose_bf16<<<128, 256, 0, stream>>>(ipw1, ipw1T, 256, 128);
    k_transpose_bf16<<<128, 256, 0, stream>>>(pw1, w1T0, 256, 128);
    k_transpose_bf16<<<128, 256, 0, stream>>>(pw1 + 32768, w1T1, 256, 128);

    // raw pool (on x)
    k_gemm<<<dim3(64, 2), 256, 0, stream>>>(xb, ipw1T, tp, POOL_);
    k_pool_sc<<<16, 256, 0, stream>>>(tp, ipb1, ipw2, ipb2, sp);
    k_pool_reduce<<<B_, 1024, 0, stream>>>(x, sp, outRaw);

    for (int l = 0; l < 2; ++l) {
        bf16* wT   = l ? wT1 : wT0;
        bf16* w1T  = l ? w1T1 : w1T0;
        float* node   = l ? node1 : node0;
        float* pooled = l ? pool1 : pool0;
        k_gemm_h<<<dim3(64, 4), 256, 0, stream>>>(xb, wT, h, hbT);
        k_srcdst<<<64, 256, 0, stream>>>(h, a_src + l * 256, a_dst + l * 256, srcM, dstT);
        k_dmax<<<8, 256, 0, stream>>>(dstT, dmaxp);
        k_attn<<<dim3(32, 4, 2), 256, 0, stream>>>(srcM, dstT, dmaxp, am, hbT, node, xb);
        k_gemm<<<dim3(64, 2), 256, 0, stream>>>(xb, w1T, tp, POOL_);
        k_pool_sc<<<16, 256, 0, stream>>>(tp, pb1 + l * POOL_, pw2 + l * POOL_, pb2 + l, sp);
        k_pool_reduce<<<B_, 1024, 0, stream>>>(node, sp, pooled);
    }
}

// Round 2
// 192.556 us; speedup vs baseline: 1.6046x; 1.6046x over previous
//
#include <hip/hip_runtime.h>
#include <hip/hip_bf16.h>

#define B_ 2
#define N_ 2048
#define HID_ 256
#define HEADS_ 4
#define D_ 64
#define POOL_ 128

typedef __bf16 bf16;
typedef __bf16 bf16x8 __attribute__((ext_vector_type(8)));
typedef float f32x4 __attribute__((ext_vector_type(4)));

__device__ __forceinline__ float fast_tanh(float x) {
    x = fminf(fmaxf(x, -15.f), 15.f);
    float t = __expf(2.f * x);
    return (t - 1.f) / (t + 1.f);
}

// ---------------- input projection: x = relu(ge*w+b), f32 + bf16 copies ----------------
__global__ void k_input_proj(const float* __restrict__ ge, const float* __restrict__ w,
                             const float* __restrict__ b, float* __restrict__ x,
                             bf16* __restrict__ xb) {
    int row = blockIdx.x;            // B*N
    int c = threadIdx.x;             // HID
    float g = ge[row];
    float v = fmaxf(g * w[c] + b[c], 0.f);
    x[row * HID_ + c] = v;
    xb[row * HID_ + c] = (bf16)v;
}

// ---------------- adjacency -> bitmask via ballot (coalesced) ----------------
__global__ void k_adjbits(const int* __restrict__ adj, unsigned* __restrict__ am) {
    int gid = blockIdx.x * 256 + threadIdx.x;   // over B*N*N
    int v = adj[gid];
    unsigned long long mask = __ballot(v > 0);
    int lane = threadIdx.x & 63;
    if (lane == 0) am[gid >> 5] = (unsigned)mask;
    else if (lane == 32) am[gid >> 5] = (unsigned)(mask >> 32);
}

// ---------------- all weight transposes fused: f32 [256][Nc] -> bf16 [Nc][256] ----------------
__global__ void k_prep(const float* __restrict__ proj_w, const float* __restrict__ ipw1,
                       const float* __restrict__ pw1, bf16* __restrict__ wT0,
                       bf16* __restrict__ wT1, bf16* __restrict__ ipw1T,
                       bf16* __restrict__ w1T0, bf16* __restrict__ w1T1) {
    int o = blockIdx.x * 256 + threadIdx.x;     // 229376 total
    const float* src; bf16* dst; int Nc, loc;
    if (o < 65536)       { src = proj_w;         dst = wT0;   Nc = 256; loc = o; }
    else if (o < 131072) { src = proj_w + 65536; dst = wT1;   Nc = 256; loc = o - 65536; }
    else if (o < 163840) { src = ipw1;           dst = ipw1T; Nc = 128; loc = o - 131072; }
    else if (o < 196608) { src = pw1;            dst = w1T0;  Nc = 128; loc = o - 163840; }
    else                 { src = pw1 + 32768;    dst = w1T1;  Nc = 128; loc = o - 196608; }
    int n = loc >> 8, k = loc & 255;
    dst[loc] = (bf16)src[k * Nc + n];
}

// ---------------- h = xb @ W (per head), epilogue: hbT bf16 transposed + src/dst dots ----------------
__global__ __launch_bounds__(256) void k_gemm_h(const bf16* __restrict__ A,
                                                const bf16* __restrict__ WT,
                                                const float* __restrict__ as,
                                                const float* __restrict__ ad,
                                                bf16* __restrict__ hbT,
                                                float* __restrict__ srcM,
                                                float* __restrict__ dstT) {
    int i0 = blockIdx.x * 64, hd = blockIdx.y;
    int n0 = hd * 64;
    int w = threadIdx.x >> 6, lane = threadIdx.x & 63, r = lane & 15, g = lane >> 4;
    const bf16* ap = A + (i0 + w * 16 + r) * 256 + g * 8;
    f32x4 acc[4] = {{0,0,0,0},{0,0,0,0},{0,0,0,0},{0,0,0,0}};
    for (int ks = 0; ks < 256; ks += 32) {
        bf16x8 af = *(const bf16x8*)(ap + ks);
        #pragma unroll
        for (int nf = 0; nf < 4; ++nf) {
            bf16x8 bfr = *(const bf16x8*)(WT + (n0 + nf * 16 + r) * 256 + ks + g * 8);
            acc[nf] = __builtin_amdgcn_mfma_f32_16x16x32_bf16(af, bfr, acc[nf], 0, 0, 0);
        }
    }
    float asv[4], adv[4];
    #pragma unroll
    for (int nf = 0; nf < 4; ++nf) {
        asv[nf] = as[hd * 64 + nf * 16 + r];
        adv[nf] = ad[hd * 64 + nf * 16 + r];
    }
    #pragma unroll
    for (int q = 0; q < 4; ++q) {
        int row = i0 + w * 16 + g * 4 + q;
        int b = row >> 11, nn = row & 2047;
        float ps = 0.f, pd = 0.f;
        #pragma unroll
        for (int nf = 0; nf < 4; ++nf) {
            float v = acc[nf][q];
            ps += v * asv[nf];
            pd += v * adv[nf];
            hbT[(((b * HEADS_ + hd) * D_) + nf * 16 + r) * N_ + nn] = (bf16)v;
        }
        ps += __shfl_xor(ps, 1); ps += __shfl_xor(ps, 2);
        ps += __shfl_xor(ps, 4); ps += __shfl_xor(ps, 8);
        pd += __shfl_xor(pd, 1); pd += __shfl_xor(pd, 2);
        pd += __shfl_xor(pd, 4); pd += __shfl_xor(pd, 8);
        if (r == 0) {
            srcM[(b * HEADS_ + hd) * N_ + nn] = ps;
            dstT[(b * HEADS_ + hd) * N_ + nn] = pd;
        }
    }
}

// ---------------- fused GAT attention: 16 rows/block, 8 waves split j, LDS combine ----------------
__global__ __launch_bounds__(512) void k_attn(const float* __restrict__ srcM,
                                              const float* __restrict__ dstT,
                                              const unsigned* __restrict__ am,
                                              const bf16* __restrict__ hbT,
                                              float* __restrict__ nodeOut,
                                              bf16* __restrict__ xbNext) {
    int it = blockIdx.x, hd = blockIdx.y, b = blockIdx.z;
    int i0 = it * 16;
    int w = threadIdx.x >> 6, lane = threadIdx.x & 63, r = lane & 15, g = lane >> 4;
    int bh = b * HEADS_ + hd;
    const float* drow = dstT + bh * N_;

    // block-wide max over dst (512 threads x 4 elements)
    __shared__ float sred[8];
    {
        float4 a0 = *(const float4*)(drow + threadIdx.x * 4);
        float m = fmaxf(fmaxf(a0.x, a0.y), fmaxf(a0.z, a0.w));
        #pragma unroll
        for (int o = 1; o < 64; o <<= 1) m = fmaxf(m, __shfl_xor(m, o));
        if (lane == 0) sred[w] = m;
    }
    __syncthreads();
    float dm = sred[0];
    #pragma unroll
    for (int k = 1; k < 8; ++k) dm = fmaxf(dm, sred[k]);

    int i = i0 + r;
    float sv = srcM[bh * N_ + i];
    float t0 = sv + dm;
    float mi = fmaxf(t0, 0.2f * t0);   // leaky(src_i + dmax) >= row max
    const unsigned* mrow = am + (b * N_ + i) * 64;
    const bf16* vbase = hbT + (long long)bh * D_ * N_;

    f32x4 acc[4] = {{0,0,0,0},{0,0,0,0},{0,0,0,0},{0,0,0,0}};
    float l = 0.f;
    int jbase = w * 256;                        // each wave: 256 j's

    for (int js = 0; js < 256; js += 32) {
        int jb = jbase + js + g * 8;
        float4 dv0 = *(const float4*)(drow + jb);
        float4 dv1 = *(const float4*)(drow + jb + 4);
        unsigned mb = (mrow[(jbase + js) >> 5] >> (g * 8)) & 0xFFu;
        float dd[8] = {dv0.x, dv0.y, dv0.z, dv0.w, dv1.x, dv1.y, dv1.z, dv1.w};
        bf16x8 af;
        float ls = 0.f;
        #pragma unroll
        for (int t = 0; t < 8; ++t) {
            float tt = sv + dd[t];
            float lv = fmaxf(tt, 0.2f * tt);
            float e2 = __expf(lv - mi);
            e2 = ((mb >> t) & 1u) ? e2 : 0.f;
            ls += e2;
            af[t] = (bf16)e2;
        }
        l += ls;
        #pragma unroll
        for (int nf = 0; nf < 4; ++nf) {
            bf16x8 vf = *(const bf16x8*)(vbase + (nf * 16 + r) * N_ + jb);
            acc[nf] = __builtin_amdgcn_mfma_f32_16x16x32_bf16(af, vf, acc[nf], 0, 0, 0);
        }
    }
    // combine the 4 g-groups within wave (disjoint j), then across 8 waves via LDS
    l += __shfl_xor(l, 16);
    l += __shfl_xor(l, 32);
    __shared__ float lred[8][16];
    __shared__ float accs[8][16][68];
    if (g == 0) lred[w][r] = l;
    #pragma unroll
    for (int nf = 0; nf < 4; ++nf)
        #pragma unroll
        for (int q = 0; q < 4; ++q)
            accs[w][g * 4 + q][nf * 16 + r] = acc[nf][q];
    __syncthreads();

    int cc = lane;
    #pragma unroll
    for (int k = 0; k < 2; ++k) {
        int rr = w * 2 + k;
        float ls = 0.f, v = 0.f;
        #pragma unroll
        for (int w2 = 0; w2 < 8; ++w2) {
            ls += lred[w2][rr];
            v += accs[w2][rr][cc];
        }
        v /= ls;
        float o = v > 0.f ? v : expm1f(v);      // elu
        int idx = (b * N_ + i0 + rr) * HID_ + hd * D_ + cc;
        nodeOut[idx] = o;
        xbNext[idx] = (bf16)o;
    }
}

// ---------------- pool score fused GEMM: s = tanh(xb@W1 + b1) . w2 + b2 ----------------
__global__ __launch_bounds__(256) void k_pool_score(const bf16* __restrict__ A,
                                                    const bf16* __restrict__ W1T,
                                                    const float* __restrict__ b1,
                                                    const float* __restrict__ w2,
                                                    const float* __restrict__ b2,
                                                    float* __restrict__ s) {
    int i0 = blockIdx.x * 64;
    int w = threadIdx.x >> 6, lane = threadIdx.x & 63, r = lane & 15, g = lane >> 4;
    const bf16* ap = A + (i0 + w * 16 + r) * 256 + g * 8;
    f32x4 acc[8] = {{0,0,0,0},{0,0,0,0},{0,0,0,0},{0,0,0,0},
                    {0,0,0,0},{0,0,0,0},{0,0,0,0},{0,0,0,0}};
    for (int ks = 0; ks < 256; ks += 32) {
        bf16x8 af = *(const bf16x8*)(ap + ks);
        #pragma unroll
        for (int nf = 0; nf < 8; ++nf) {
            bf16x8 bfr = *(const bf16x8*)(W1T + (nf * 16 + r) * 256 + ks + g * 8);
            acc[nf] = __builtin_amdgcn_mfma_f32_16x16x32_bf16(af, bfr, acc[nf], 0, 0, 0);
        }
    }
    float b1v[8], w2v[8];
    #pragma unroll
    for (int nf = 0; nf < 8; ++nf) {
        b1v[nf] = b1[nf * 16 + r];
        w2v[nf] = w2[nf * 16 + r];
    }
    float b2v = b2[0];
    #pragma unroll
    for (int q = 0; q < 4; ++q) {
        float p = 0.f;
        #pragma unroll
        for (int nf = 0; nf < 8; ++nf) p += fast_tanh(acc[nf][q] + b1v[nf]) * w2v[nf];
        p += __shfl_xor(p, 1); p += __shfl_xor(p, 2);
        p += __shfl_xor(p, 4); p += __shfl_xor(p, 8);
        if (r == 0) s[i0 + w * 16 + g * 4 + q] = p + b2v;
    }
}

// ---------------- pool softmax stats: m and Z per batch ----------------
__global__ __launch_bounds__(256) void k_pool_stats(const float* __restrict__ s,
                                                    float* __restrict__ mz) {
    int b = blockIdx.x, tid = threadIdx.x, lane = tid & 63, w = tid >> 6;
    const float* sp = s + b * N_;
    float v[8], m = -3e38f;
    #pragma unroll
    for (int k = 0; k < 8; ++k) { v[k] = sp[tid + k * 256]; m = fmaxf(m, v[k]); }
    #pragma unroll
    for (int o = 1; o < 64; o <<= 1) m = fmaxf(m, __shfl_xor(m, o));
    __shared__ float red[8];
    if (lane == 0) red[w] = m;
    __syncthreads();
    m = fmaxf(fmaxf(red[0], red[1]), fmaxf(red[2], red[3]));
    float z = 0.f;
    #pragma unroll
    for (int k = 0; k < 8; ++k) z += __expf(v[k] - m);
    #pragma unroll
    for (int o = 1; o < 64; o <<= 1) z += __shfl_xor(z, o);
    __syncthreads();
    if (lane == 0) red[4 + w] = z;
    __syncthreads();
    if (tid == 0) {
        mz[b * 2] = m;
        mz[b * 2 + 1] = red[4] + red[5] + red[6] + red[7];
    }
}

// ---------------- pool weighted partial sums: 32 rows per block ----------------
__global__ __launch_bounds__(256) void k_pool_wsum(const float* __restrict__ xsrc,
                                                   const float* __restrict__ s,
                                                   const float* __restrict__ mz,
                                                   float* __restrict__ part) {
    int b = blockIdx.x, ch = blockIdx.y, c = threadIdx.x;
    __shared__ float e[32];
    float m = mz[b * 2];
    int n0 = ch * 32;
    if (c < 32) e[c] = __expf(s[b * N_ + n0 + c] - m);
    __syncthreads();
    const float* xp = xsrc + (long long)(b * N_ + n0) * HID_ + c;
    float acc = 0.f;
    #pragma unroll 8
    for (int n = 0; n < 32; ++n) acc += e[n] * xp[n * HID_];
    part[(b * 64 + ch) * HID_ + c] = acc;
}

// ---------------- pool final reduce ----------------
__global__ __launch_bounds__(256) void k_pool_final(const float* __restrict__ part,
                                                    const float* __restrict__ mz,
                                                    float* __restrict__ out) {
    int b = blockIdx.x, c = threadIdx.x;
    float acc = 0.f;
    #pragma unroll 8
    for (int ch = 0; ch < 64; ++ch) acc += part[(b * 64 + ch) * HID_ + c];
    out[b * HID_ + c] = acc / mz[b * 2 + 1];
}

extern "C" void kernel_launch(void* const* d_in, const int* in_sizes, int n_in,
                              void* d_out, int out_size, void* d_ws, size_t ws_size,
                              hipStream_t stream) {
    const float* ge     = (const float*)d_in[0];
    const int*   adj    = (const int*)d_in[1];
    const float* in_w   = (const float*)d_in[2];
    const float* in_b   = (const float*)d_in[3];
    const float* proj_w = (const float*)d_in[4];
    const float* a_src  = (const float*)d_in[5];
    const float* a_dst  = (const float*)d_in[6];
    const float* pw1    = (const float*)d_in[7];
    const float* pb1    = (const float*)d_in[8];
    const float* pw2    = (const float*)d_in[9];
    const float* pb2    = (const float*)d_in[10];
    const float* ipw1   = (const float*)d_in[11];
    const float* ipb1   = (const float*)d_in[12];
    const float* ipw2   = (const float*)d_in[13];
    const float* ipb2   = (const float*)d_in[14];

    char* ws = (char*)d_ws;
    float*    x     = (float*)(ws + 0);            // 4 MB
    bf16*     xb    = (bf16*)(ws + 4194304);       // 2 MB
    bf16*     hbT   = (bf16*)(ws + 6291456);       // 2 MB
    float*    sp    = (float*)(ws + 8388608);      // 16 KB
    float*    srcM  = (float*)(ws + 8404992);      // 64 KB
    float*    dstT  = (float*)(ws + 8470528);      // 64 KB
    unsigned* am    = (unsigned*)(ws + 8536064);   // 1 MB
    bf16*     wT0   = (bf16*)(ws + 9584640);       // 128 KB
    bf16*     wT1   = wT0 + 65536;                 // 128 KB
    bf16*     ipw1T = wT1 + 65536;                 // 64 KB
    bf16*     w1T0  = ipw1T + 32768;               // 64 KB
    bf16*     w1T1  = w1T0 + 32768;                // 64 KB
    float*    part  = (float*)(ws + 10043392);     // 128 KB
    float*    mz    = (float*)(ws + 10174464);     // 16 B

    float* outRaw = (float*)d_out;
    float* node0  = outRaw + 512;
    float* node1  = node0 + 1048576;
    float* pool0  = node1 + 1048576;
    float* pool1  = pool0 + 512;

    k_input_proj<<<B_ * N_, HID_, 0, stream>>>(ge, in_w, in_b, x, xb);
    k_adjbits<<<B_ * N_ * N_ / 256, 256, 0, stream>>>(adj, am);
    k_prep<<<896, 256, 0, stream>>>(proj_w, ipw1, pw1, wT0, wT1, ipw1T, w1T0, w1T1);

    // raw pool (on x)
    k_pool_score<<<64, 256, 0, stream>>>(xb, ipw1T, ipb1, ipw2, ipb2, sp);
    k_pool_stats<<<B_, 256, 0, stream>>>(sp, mz);
    k_pool_wsum<<<dim3(B_, 64), 256, 0, stream>>>(x, sp, mz, part);
    k_pool_final<<<B_, 256, 0, stream>>>(part, mz, outRaw);

    for (int l = 0; l < 2; ++l) {
        bf16* wT   = l ? wT1 : wT0;
        bf16* w1T  = l ? w1T1 : w1T0;
        float* node   = l ? node1 : node0;
        float* pooled = l ? pool1 : pool0;
        k_gemm_h<<<dim3(64, 4), 256, 0, stream>>>(xb, wT, a_src + l * 256, a_dst + l * 256,
                                                  hbT, srcM, dstT);
        k_attn<<<dim3(128, 4, 2), 512, 0, stream>>>(srcM, dstT, am, hbT, node, xb);
        k_pool_score<<<64, 256, 0, stream>>>(xb, w1T, pb1 + l * POOL_, pw2 + l * POOL_,
                                             pb2 + l, sp);
        k_pool_stats<<<B_, 256, 0, stream>>>(sp, mz);
        k_pool_wsum<<<dim3(B_, 64), 256, 0, stream>>>(node, sp, mz, part);
        k_pool_final<<<B_, 256, 0, stream>>>(part, mz, pooled);
    }
}

// Round 3
// 174.363 us; speedup vs baseline: 1.7721x; 1.1043x over previous
//
#include <hip/hip_runtime.h>
#include <hip/hip_bf16.h>

#define B_ 2
#define N_ 2048
#define HID_ 256
#define HEADS_ 4
#define D_ 64
#define POOL_ 128

typedef __bf16 bf16;
typedef __bf16 bf16x8 __attribute__((ext_vector_type(8)));
typedef float f32x4 __attribute__((ext_vector_type(4)));

__device__ __forceinline__ float fast_tanh(float x) {
    x = fminf(fmaxf(x, -15.f), 15.f);
    float t = __expf(2.f * x);
    return (t - 1.f) / (t + 1.f);
}

// ---------------- input projection: x = relu(ge*w+b), f32 + bf16 copies ----------------
__global__ void k_input_proj(const float* __restrict__ ge, const float* __restrict__ w,
                             const float* __restrict__ b, float* __restrict__ x,
                             bf16* __restrict__ xb) {
    int row = blockIdx.x;            // B*N
    int c = threadIdx.x;             // HID
    float g = ge[row];
    float v = fmaxf(g * w[c] + b[c], 0.f);
    x[row * HID_ + c] = v;
    xb[row * HID_ + c] = (bf16)v;
}

// ---------------- adjacency -> bitmask via ballot (coalesced) ----------------
__global__ void k_adjbits(const int* __restrict__ adj, unsigned* __restrict__ am) {
    int gid = blockIdx.x * 256 + threadIdx.x;   // over B*N*N
    int v = adj[gid];
    unsigned long long mask = __ballot(v > 0);
    int lane = threadIdx.x & 63;
    if (lane == 0) am[gid >> 5] = (unsigned)mask;
    else if (lane == 32) am[gid >> 5] = (unsigned)(mask >> 32);
}

// ---------------- all weight transposes fused: f32 [256][Nc] -> bf16 [Nc][256] ----------------
__global__ void k_prep(const float* __restrict__ proj_w, const float* __restrict__ ipw1,
                       const float* __restrict__ pw1, bf16* __restrict__ wT0,
                       bf16* __restrict__ wT1, bf16* __restrict__ ipw1T,
                       bf16* __restrict__ w1T0, bf16* __restrict__ w1T1) {
    int o = blockIdx.x * 256 + threadIdx.x;     // 229376 total
    const float* src; bf16* dst; int Nc, loc;
    if (o < 65536)       { src = proj_w;         dst = wT0;   Nc = 256; loc = o; }
    else if (o < 131072) { src = proj_w + 65536; dst = wT1;   Nc = 256; loc = o - 65536; }
    else if (o < 163840) { src = ipw1;           dst = ipw1T; Nc = 128; loc = o - 131072; }
    else if (o < 196608) { src = pw1;            dst = w1T0;  Nc = 128; loc = o - 163840; }
    else                 { src = pw1 + 32768;    dst = w1T1;  Nc = 128; loc = o - 196608; }
    int n = loc >> 8, k = loc & 255;
    dst[loc] = (bf16)src[k * Nc + n];
}

// ---------------- h = xb @ W (per head), epilogue: hbT bf16 transposed + src/dst dots ----------------
__global__ __launch_bounds__(256) void k_gemm_h(const bf16* __restrict__ A,
                                                const bf16* __restrict__ WT,
                                                const float* __restrict__ as,
                                                const float* __restrict__ ad,
                                                bf16* __restrict__ hbT,
                                                float* __restrict__ srcM,
                                                float* __restrict__ dstT) {
    int i0 = blockIdx.x * 64, hd = blockIdx.y;
    int n0 = hd * 64;
    int w = threadIdx.x >> 6, lane = threadIdx.x & 63, r = lane & 15, g = lane >> 4;
    const bf16* ap = A + (i0 + w * 16 + r) * 256 + g * 8;
    f32x4 acc[4] = {{0,0,0,0},{0,0,0,0},{0,0,0,0},{0,0,0,0}};
    for (int ks = 0; ks < 256; ks += 32) {
        bf16x8 af = *(const bf16x8*)(ap + ks);
        #pragma unroll
        for (int nf = 0; nf < 4; ++nf) {
            bf16x8 bfr = *(const bf16x8*)(WT + (n0 + nf * 16 + r) * 256 + ks + g * 8);
            acc[nf] = __builtin_amdgcn_mfma_f32_16x16x32_bf16(af, bfr, acc[nf], 0, 0, 0);
        }
    }
    float asv[4], adv[4];
    #pragma unroll
    for (int nf = 0; nf < 4; ++nf) {
        asv[nf] = as[hd * 64 + nf * 16 + r];
        adv[nf] = ad[hd * 64 + nf * 16 + r];
    }
    #pragma unroll
    for (int q = 0; q < 4; ++q) {
        int row = i0 + w * 16 + g * 4 + q;
        int b = row >> 11, nn = row & 2047;
        float ps = 0.f, pd = 0.f;
        #pragma unroll
        for (int nf = 0; nf < 4; ++nf) {
            float v = acc[nf][q];
            ps += v * asv[nf];
            pd += v * adv[nf];
            hbT[(((b * HEADS_ + hd) * D_) + nf * 16 + r) * N_ + nn] = (bf16)v;
        }
        ps += __shfl_xor(ps, 1); ps += __shfl_xor(ps, 2);
        ps += __shfl_xor(ps, 4); ps += __shfl_xor(ps, 8);
        pd += __shfl_xor(pd, 1); pd += __shfl_xor(pd, 2);
        pd += __shfl_xor(pd, 4); pd += __shfl_xor(pd, 8);
        if (r == 0) {
            srcM[(b * HEADS_ + hd) * N_ + nn] = ps;
            dstT[(b * HEADS_ + hd) * N_ + nn] = pd;
        }
    }
}

// ---------------- fused GAT attention v3: LDS dst row, register masks, unrolled ----------------
__global__ __launch_bounds__(512, 4) void k_attn(const float* __restrict__ srcM,
                                                 const float* __restrict__ dstT,
                                                 const unsigned* __restrict__ am,
                                                 const bf16* __restrict__ hbT,
                                                 float* __restrict__ nodeOut,
                                                 bf16* __restrict__ xbNext) {
    int it = blockIdx.x, hd = blockIdx.y, b = blockIdx.z;
    int i0 = it * 16;
    int w = threadIdx.x >> 6, lane = threadIdx.x & 63, r = lane & 15, g = lane >> 4;
    int bh = b * HEADS_ + hd;
    const float* drow = dstT + bh * N_;

    __shared__ float dls[N_];
    __shared__ float lred[8][16];
    __shared__ float accs[8][16][68];

    // stage dst row in LDS (coalesced)
    *(float4*)(dls + threadIdx.x * 4) = *(const float4*)(drow + threadIdx.x * 4);

    // preload this wave's 8 adjacency mask words for its 16 rows
    int i = i0 + r;
    const unsigned* mrow = am + ((long long)(b * N_ + i)) * 64 + w * 8;
    uint4 m0 = *(const uint4*)(mrow);
    uint4 m1 = *(const uint4*)(mrow + 4);
    unsigned mw[8] = {m0.x, m0.y, m0.z, m0.w, m1.x, m1.y, m1.z, m1.w};
    float sv = srcM[bh * N_ + i];
    const bf16* vbase = hbT + (long long)bh * D_ * N_;

    f32x4 acc[4] = {{0,0,0,0},{0,0,0,0},{0,0,0,0},{0,0,0,0}};
    float l = 0.f;
    int jbase = w * 256;                        // each wave owns 256 j's

    __syncthreads();

    #pragma unroll
    for (int js = 0; js < 8; ++js) {
        int jb = jbase + js * 32 + g * 8;
        float4 dv0 = *(const float4*)(dls + jb);
        float4 dv1 = *(const float4*)(dls + jb + 4);
        unsigned mb = (mw[js] >> (g * 8)) & 0xFFu;
        float dd[8] = {dv0.x, dv0.y, dv0.z, dv0.w, dv1.x, dv1.y, dv1.z, dv1.w};
        bf16x8 af;
        float es[8];
        #pragma unroll
        for (int t = 0; t < 8; ++t) {
            float tt = sv + dd[t];
            float lv = fmaxf(tt, 0.2f * tt);      // leaky_relu(0.2); exp is safe unshifted
            float e2 = __expf(lv);
            e2 = ((mb >> t) & 1u) ? e2 : 0.f;
            es[t] = e2;
            af[t] = (bf16)e2;
        }
        l += ((es[0] + es[1]) + (es[2] + es[3])) + ((es[4] + es[5]) + (es[6] + es[7]));
        #pragma unroll
        for (int nf = 0; nf < 4; ++nf) {
            bf16x8 vf = *(const bf16x8*)(vbase + (nf * 16 + r) * N_ + jb);
            acc[nf] = __builtin_amdgcn_mfma_f32_16x16x32_bf16(af, vf, acc[nf], 0, 0, 0);
        }
    }
    // combine g-groups within wave (disjoint j), then across 8 waves via LDS
    l += __shfl_xor(l, 16);
    l += __shfl_xor(l, 32);
    if (g == 0) lred[w][r] = l;
    #pragma unroll
    for (int nf = 0; nf < 4; ++nf)
        #pragma unroll
        for (int q = 0; q < 4; ++q)
            accs[w][g * 4 + q][nf * 16 + r] = acc[nf][q];
    __syncthreads();

    int cc = lane;
    #pragma unroll
    for (int k = 0; k < 2; ++k) {
        int rr = w * 2 + k;
        float ls = 0.f, v = 0.f;
        #pragma unroll
        for (int w2 = 0; w2 < 8; ++w2) {
            ls += lred[w2][rr];
            v += accs[w2][rr][cc];
        }
        v /= ls;
        float o = v > 0.f ? v : expm1f(v);      // elu
        int idx = (b * N_ + i0 + rr) * HID_ + hd * D_ + cc;
        nodeOut[idx] = o;
        xbNext[idx] = (bf16)o;
    }
}

// ---------------- pool score fused GEMM: e = exp(tanh(xb@W1 + b1) . w2 + b2) ----------------
__global__ __launch_bounds__(256) void k_pool_score(const bf16* __restrict__ A,
                                                    const bf16* __restrict__ W1T,
                                                    const float* __restrict__ b1,
                                                    const float* __restrict__ w2,
                                                    const float* __restrict__ b2,
                                                    float* __restrict__ e) {
    int i0 = blockIdx.x * 64;
    int w = threadIdx.x >> 6, lane = threadIdx.x & 63, r = lane & 15, g = lane >> 4;
    const bf16* ap = A + (i0 + w * 16 + r) * 256 + g * 8;
    f32x4 acc[8] = {{0,0,0,0},{0,0,0,0},{0,0,0,0},{0,0,0,0},
                    {0,0,0,0},{0,0,0,0},{0,0,0,0},{0,0,0,0}};
    for (int ks = 0; ks < 256; ks += 32) {
        bf16x8 af = *(const bf16x8*)(ap + ks);
        #pragma unroll
        for (int nf = 0; nf < 8; ++nf) {
            bf16x8 bfr = *(const bf16x8*)(W1T + (nf * 16 + r) * 256 + ks + g * 8);
            acc[nf] = __builtin_amdgcn_mfma_f32_16x16x32_bf16(af, bfr, acc[nf], 0, 0, 0);
        }
    }
    float b1v[8], w2v[8];
    #pragma unroll
    for (int nf = 0; nf < 8; ++nf) {
        b1v[nf] = b1[nf * 16 + r];
        w2v[nf] = w2[nf * 16 + r];
    }
    float b2v = b2[0];
    #pragma unroll
    for (int q = 0; q < 4; ++q) {
        float p = 0.f;
        #pragma unroll
        for (int nf = 0; nf < 8; ++nf) p += fast_tanh(acc[nf][q] + b1v[nf]) * w2v[nf];
        p += __shfl_xor(p, 1); p += __shfl_xor(p, 2);
        p += __shfl_xor(p, 4); p += __shfl_xor(p, 8);
        if (r == 0) e[i0 + w * 16 + g * 4 + q] = __expf(p + b2v);  // |s| small: no max shift
    }
}

// ---------------- pool weighted partial sums: 16 rows per block ----------------
__global__ __launch_bounds__(256) void k_pool_wsum(const float* __restrict__ xsrc,
                                                   const float* __restrict__ e,
                                                   float* __restrict__ part) {
    int b = blockIdx.x, ch = blockIdx.y, c = threadIdx.x;
    __shared__ float el[16];
    int n0 = ch * 16;
    if (c < 16) el[c] = e[b * N_ + n0 + c];
    __syncthreads();
    const float* xp = xsrc + (long long)(b * N_ + n0) * HID_ + c;
    float acc = 0.f;
    #pragma unroll
    for (int n = 0; n < 16; ++n) acc += el[n] * xp[n * HID_];
    part[(b * 128 + ch) * HID_ + c] = acc;
}

// ---------------- pool final reduce: Z from e, sum 128 partials ----------------
__global__ __launch_bounds__(256) void k_pool_final(const float* __restrict__ part,
                                                    const float* __restrict__ e,
                                                    float* __restrict__ out) {
    int b = blockIdx.x, c = threadIdx.x;
    int lane = c & 63, w = c >> 6;
    float z = 0.f;
    #pragma unroll
    for (int k = 0; k < 8; ++k) z += e[b * N_ + c + k * 256];
    #pragma unroll
    for (int o = 1; o < 64; o <<= 1) z += __shfl_xor(z, o);
    __shared__ float red[4];
    if (lane == 0) red[w] = z;
    __syncthreads();
    float Z = red[0] + red[1] + red[2] + red[3];
    float acc = 0.f;
    #pragma unroll 8
    for (int ch = 0; ch < 128; ++ch) acc += part[(b * 128 + ch) * HID_ + c];
    out[b * HID_ + c] = acc / Z;
}

extern "C" void kernel_launch(void* const* d_in, const int* in_sizes, int n_in,
                              void* d_out, int out_size, void* d_ws, size_t ws_size,
                              hipStream_t stream) {
    const float* ge     = (const float*)d_in[0];
    const int*   adj    = (const int*)d_in[1];
    const float* in_w   = (const float*)d_in[2];
    const float* in_b   = (const float*)d_in[3];
    const float* proj_w = (const float*)d_in[4];
    const float* a_src  = (const float*)d_in[5];
    const float* a_dst  = (const float*)d_in[6];
    const float* pw1    = (const float*)d_in[7];
    const float* pb1    = (const float*)d_in[8];
    const float* pw2    = (const float*)d_in[9];
    const float* pb2    = (const float*)d_in[10];
    const float* ipw1   = (const float*)d_in[11];
    const float* ipb1   = (const float*)d_in[12];
    const float* ipw2   = (const float*)d_in[13];
    const float* ipb2   = (const float*)d_in[14];

    char* ws = (char*)d_ws;
    float*    x     = (float*)(ws + 0);            // 4 MB
    bf16*     xb    = (bf16*)(ws + 4194304);       // 2 MB
    bf16*     hbT   = (bf16*)(ws + 6291456);       // 2 MB
    float*    sp    = (float*)(ws + 8388608);      // 16 KB
    float*    srcM  = (float*)(ws + 8404992);      // 64 KB
    float*    dstT  = (float*)(ws + 8470528);      // 64 KB
    unsigned* am    = (unsigned*)(ws + 8536064);   // 1 MB
    bf16*     wT0   = (bf16*)(ws + 9584640);       // 128 KB
    bf16*     wT1   = wT0 + 65536;                 // 128 KB
    bf16*     ipw1T = wT1 + 65536;                 // 64 KB
    bf16*     w1T0  = ipw1T + 32768;               // 64 KB
    bf16*     w1T1  = w1T0 + 32768;                // 64 KB
    float*    part  = (float*)(ws + 10043392);     // 256 KB
    float*    mz    = (float*)(ws + 10305536);     // unused

    float* outRaw = (float*)d_out;
    float* node0  = outRaw + 512;
    float* node1  = node0 + 1048576;
    float* pool0  = node1 + 1048576;
    float* pool1  = pool0 + 512;
    (void)mz;

    k_input_proj<<<B_ * N_, HID_, 0, stream>>>(ge, in_w, in_b, x, xb);
    k_adjbits<<<B_ * N_ * N_ / 256, 256, 0, stream>>>(adj, am);
    k_prep<<<896, 256, 0, stream>>>(proj_w, ipw1, pw1, wT0, wT1, ipw1T, w1T0, w1T1);

    // raw pool (on x)
    k_pool_score<<<64, 256, 0, stream>>>(xb, ipw1T, ipb1, ipw2, ipb2, sp);
    k_pool_wsum<<<dim3(B_, 128), 256, 0, stream>>>(x, sp, part);
    k_pool_final<<<B_, 256, 0, stream>>>(part, sp, outRaw);

    for (int l = 0; l < 2; ++l) {
        bf16* wT   = l ? wT1 : wT0;
        bf16* w1T  = l ? w1T1 : w1T0;
        float* node   = l ? node1 : node0;
        float* pooled = l ? pool1 : pool0;
        k_gemm_h<<<dim3(64, 4), 256, 0, stream>>>(xb, wT, a_src + l * 256, a_dst + l * 256,
                                                  hbT, srcM, dstT);
        k_attn<<<dim3(128, 4, 2), 512, 0, stream>>>(srcM, dstT, am, hbT, node, xb);
        k_pool_score<<<64, 256, 0, stream>>>(xb, w1T, pb1 + l * POOL_, pw2 + l * POOL_,
                                             pb2 + l, sp);
        k_pool_wsum<<<dim3(B_, 128), 256, 0, stream>>>(node, sp, part);
        k_pool_final<<<B_, 256, 0, stream>>>(part, sp, pooled);
    }
}

// Round 4
// 161.887 us; speedup vs baseline: 1.9086x; 1.0771x over previous
//
#include <hip/hip_runtime.h>
#include <hip/hip_bf16.h>

#define B_ 2
#define N_ 2048
#define HID_ 256
#define HEADS_ 4
#define D_ 64
#define POOL_ 128

typedef __bf16 bf16;
typedef __bf16 bf16x8 __attribute__((ext_vector_type(8)));
typedef float f32x4 __attribute__((ext_vector_type(4)));

__device__ __forceinline__ float fast_tanh(float x) {
    x = fminf(fmaxf(x, -15.f), 15.f);
    float t = __expf(2.f * x);
    return (t - 1.f) / (t + 1.f);
}

// ---------------- input projection: x = relu(ge*w+b), f32 + bf16 copies ----------------
__global__ void k_input_proj(const float* __restrict__ ge, const float* __restrict__ w,
                             const float* __restrict__ b, float* __restrict__ x,
                             bf16* __restrict__ xb) {
    int row = blockIdx.x;            // B*N
    int c = threadIdx.x;             // HID
    float g = ge[row];
    float v = fmaxf(g * w[c] + b[c], 0.f);
    x[row * HID_ + c] = v;
    xb[row * HID_ + c] = (bf16)v;
}

// ---------------- adjacency -> bitmask via ballot (coalesced) ----------------
__global__ void k_adjbits(const int* __restrict__ adj, unsigned* __restrict__ am) {
    int gid = blockIdx.x * 256 + threadIdx.x;   // over B*N*N
    int v = adj[gid];
    unsigned long long mask = __ballot(v > 0);
    int lane = threadIdx.x & 63;
    if (lane == 0) am[gid >> 5] = (unsigned)mask;
    else if (lane == 32) am[gid >> 5] = (unsigned)(mask >> 32);
}

// ---------------- all weight transposes fused: f32 [256][Nc] -> bf16 [Nc][256] ----------------
__global__ void k_prep(const float* __restrict__ proj_w, const float* __restrict__ ipw1,
                       const float* __restrict__ pw1, bf16* __restrict__ wT0,
                       bf16* __restrict__ wT1, bf16* __restrict__ ipw1T,
                       bf16* __restrict__ w1T0, bf16* __restrict__ w1T1) {
    int o = blockIdx.x * 256 + threadIdx.x;     // 229376 total
    const float* src; bf16* dst; int Nc, loc;
    if (o < 65536)       { src = proj_w;         dst = wT0;   Nc = 256; loc = o; }
    else if (o < 131072) { src = proj_w + 65536; dst = wT1;   Nc = 256; loc = o - 65536; }
    else if (o < 163840) { src = ipw1;           dst = ipw1T; Nc = 128; loc = o - 131072; }
    else if (o < 196608) { src = pw1;            dst = w1T0;  Nc = 128; loc = o - 163840; }
    else                 { src = pw1 + 32768;    dst = w1T1;  Nc = 128; loc = o - 196608; }
    int n = loc >> 8, k = loc & 255;
    dst[loc] = (bf16)src[k * Nc + n];
}

// ---------------- h = xb @ W (per head); epilogue: src/dst dots + LDS-transposed hbT ----------------
__global__ __launch_bounds__(256) void k_gemm_h(const bf16* __restrict__ A,
                                                const bf16* __restrict__ WT,
                                                const float* __restrict__ as,
                                                const float* __restrict__ ad,
                                                bf16* __restrict__ hbT,
                                                float* __restrict__ srcM,
                                                float* __restrict__ dstT) {
    int i0 = blockIdx.x * 64, hd = blockIdx.y;
    int n0 = hd * 64;
    int w = threadIdx.x >> 6, lane = threadIdx.x & 63, r = lane & 15, g = lane >> 4;
    const bf16* ap = A + (i0 + w * 16 + r) * 256 + g * 8;
    f32x4 acc[4] = {{0,0,0,0},{0,0,0,0},{0,0,0,0},{0,0,0,0}};
    for (int ks = 0; ks < 256; ks += 32) {
        bf16x8 af = *(const bf16x8*)(ap + ks);
        #pragma unroll
        for (int nf = 0; nf < 4; ++nf) {
            bf16x8 bfr = *(const bf16x8*)(WT + (n0 + nf * 16 + r) * 256 + ks + g * 8);
            acc[nf] = __builtin_amdgcn_mfma_f32_16x16x32_bf16(af, bfr, acc[nf], 0, 0, 0);
        }
    }
    int b = i0 >> 11, nbase = i0 & 2047;
    int bh = b * HEADS_ + hd;
    float asv[4], adv[4];
    #pragma unroll
    for (int nf = 0; nf < 4; ++nf) {
        asv[nf] = as[hd * 64 + nf * 16 + r];
        adv[nf] = ad[hd * 64 + nf * 16 + r];
    }
    __shared__ float tr[64][65];
    #pragma unroll
    for (int q = 0; q < 4; ++q) {
        int ln = w * 16 + g * 4 + q;
        float ps = 0.f, pd = 0.f;
        #pragma unroll
        for (int nf = 0; nf < 4; ++nf) {
            float v = acc[nf][q];
            ps += v * asv[nf];
            pd += v * adv[nf];
            tr[nf * 16 + r][ln] = v;
        }
        ps += __shfl_xor(ps, 1); ps += __shfl_xor(ps, 2);
        ps += __shfl_xor(ps, 4); ps += __shfl_xor(ps, 8);
        pd += __shfl_xor(pd, 1); pd += __shfl_xor(pd, 2);
        pd += __shfl_xor(pd, 4); pd += __shfl_xor(pd, 8);
        if (r == 0) {
            srcM[bh * N_ + nbase + ln] = ps;
            dstT[bh * N_ + nbase + ln] = pd;
        }
    }
    __syncthreads();
    // coalesced hbT write: [bh][d][n]
    int ld = threadIdx.x >> 2, ln0 = (threadIdx.x & 3) * 16;
    bf16x8 o0, o1;
    #pragma unroll
    for (int e = 0; e < 8; ++e) {
        o0[e] = (bf16)tr[ld][ln0 + e];
        o1[e] = (bf16)tr[ld][ln0 + 8 + e];
    }
    bf16* hp = hbT + ((long long)bh * D_ + ld) * N_ + nbase + ln0;
    *(bf16x8*)(hp) = o0;
    *(bf16x8*)(hp + 8) = o1;
}

// ---------------- fused GAT attention v4: LDS-tiled V, register-prefetched staging ----------------
__global__ __launch_bounds__(512, 4) void k_attn(const float* __restrict__ srcM,
                                                 const float* __restrict__ dstT,
                                                 const unsigned* __restrict__ am,
                                                 const bf16* __restrict__ hbT,
                                                 float* __restrict__ nodeOut,
                                                 bf16* __restrict__ xbNext) {
    int it = blockIdx.x, hd = blockIdx.y, b = blockIdx.z;
    int i0 = it * 16;
    int tid = threadIdx.x;
    int w = tid >> 6, lane = tid & 63, r = lane & 15, g = lane >> 4;
    int bh = b * HEADS_ + hd;
    const float* drow = dstT + bh * N_;
    const bf16* vbase = hbT + (long long)bh * D_ * N_;

    // vtile [64][264] bf16 (33792 B) aliased with epilogue accs [8][16][68] f32 (34816 B)
    __shared__ __align__(16) char smem[34816];
    bf16* vt = (bf16*)smem;
    float (*accs)[16][68] = (float (*)[16][68])smem;
    __shared__ float lred[8][16];

    int i = i0 + r;
    const unsigned* mrow = am + ((long long)(b * N_ + i)) * 64;
    float sv = srcM[bh * N_ + i];

    f32x4 acc[4] = {{0,0,0,0},{0,0,0,0},{0,0,0,0},{0,0,0,0}};
    float l = 0.f;

    // prefetch tile 0 into registers
    bf16x8 st[4];
    #pragma unroll
    for (int k = 0; k < 4; ++k) {
        int s = tid + k * 512, d = s >> 5, seg = s & 31;
        st[k] = *(const bf16x8*)(vbase + d * N_ + seg * 8);
    }

    #pragma unroll
    for (int t = 0; t < 8; ++t) {
        // commit staged tile to LDS
        #pragma unroll
        for (int k = 0; k < 4; ++k) {
            int s = tid + k * 512, d = s >> 5, seg = s & 31;
            *(bf16x8*)(vt + d * 264 + seg * 8) = st[k];
        }
        __syncthreads();
        // prefetch next tile (latency hides under compute below)
        if (t < 7) {
            #pragma unroll
            for (int k = 0; k < 4; ++k) {
                int s = tid + k * 512, d = s >> 5, seg = s & 31;
                st[k] = *(const bf16x8*)(vbase + d * N_ + (t + 1) * 256 + seg * 8);
            }
        }
        // this wave's j-slice within tile: 32 j's
        int jb = t * 256 + w * 32 + g * 8;
        float4 dv0 = *(const float4*)(drow + jb);
        float4 dv1 = *(const float4*)(drow + jb + 4);
        unsigned mb = (mrow[t * 8 + w] >> (g * 8)) & 0xFFu;
        float dd[8] = {dv0.x, dv0.y, dv0.z, dv0.w, dv1.x, dv1.y, dv1.z, dv1.w};
        bf16x8 af;
        float es[8];
        #pragma unroll
        for (int tt = 0; tt < 8; ++tt) {
            float s2 = sv + dd[tt];
            float lv = fmaxf(s2, 0.2f * s2);      // leaky_relu(0.2); exp safe unshifted
            float e2 = __expf(lv);
            e2 = ((mb >> tt) & 1u) ? e2 : 0.f;
            es[tt] = e2;
            af[tt] = (bf16)e2;
        }
        l += ((es[0] + es[1]) + (es[2] + es[3])) + ((es[4] + es[5]) + (es[6] + es[7]));
        #pragma unroll
        for (int nf = 0; nf < 4; ++nf) {
            bf16x8 vf = *(const bf16x8*)(vt + (nf * 16 + r) * 264 + w * 32 + g * 8);
            acc[nf] = __builtin_amdgcn_mfma_f32_16x16x32_bf16(af, vf, acc[nf], 0, 0, 0);
        }
        __syncthreads();
    }

    // combine g-groups within wave (disjoint j), then across 8 waves via LDS (aliases vt)
    l += __shfl_xor(l, 16);
    l += __shfl_xor(l, 32);
    if (g == 0) lred[w][r] = l;
    #pragma unroll
    for (int nf = 0; nf < 4; ++nf)
        #pragma unroll
        for (int q = 0; q < 4; ++q)
            accs[w][g * 4 + q][nf * 16 + r] = acc[nf][q];
    __syncthreads();

    int cc = lane;
    #pragma unroll
    for (int k = 0; k < 2; ++k) {
        int rr = w * 2 + k;
        float ls = 0.f, v = 0.f;
        #pragma unroll
        for (int w2 = 0; w2 < 8; ++w2) {
            ls += lred[w2][rr];
            v += accs[w2][rr][cc];
        }
        v /= ls;
        float o = v > 0.f ? v : expm1f(v);      // elu
        int idx = (b * N_ + i0 + rr) * HID_ + hd * D_ + cc;
        nodeOut[idx] = o;
        xbNext[idx] = (bf16)o;
    }
}

// ---------------- pool score fused GEMM: e = exp(tanh(xb@W1 + b1) . w2 + b2) ----------------
__global__ __launch_bounds__(256) void k_pool_score(const bf16* __restrict__ A,
                                                    const bf16* __restrict__ W1T,
                                                    const float* __restrict__ b1,
                                                    const float* __restrict__ w2,
                                                    const float* __restrict__ b2,
                                                    float* __restrict__ e) {
    int i0 = blockIdx.x * 64;
    int w = threadIdx.x >> 6, lane = threadIdx.x & 63, r = lane & 15, g = lane >> 4;
    const bf16* ap = A + (i0 + w * 16 + r) * 256 + g * 8;
    f32x4 acc[8] = {{0,0,0,0},{0,0,0,0},{0,0,0,0},{0,0,0,0},
                    {0,0,0,0},{0,0,0,0},{0,0,0,0},{0,0,0,0}};
    for (int ks = 0; ks < 256; ks += 32) {
        bf16x8 af = *(const bf16x8*)(ap + ks);
        #pragma unroll
        for (int nf = 0; nf < 8; ++nf) {
            bf16x8 bfr = *(const bf16x8*)(W1T + (nf * 16 + r) * 256 + ks + g * 8);
            acc[nf] = __builtin_amdgcn_mfma_f32_16x16x32_bf16(af, bfr, acc[nf], 0, 0, 0);
        }
    }
    float b1v[8], w2v[8];
    #pragma unroll
    for (int nf = 0; nf < 8; ++nf) {
        b1v[nf] = b1[nf * 16 + r];
        w2v[nf] = w2[nf * 16 + r];
    }
    float b2v = b2[0];
    #pragma unroll
    for (int q = 0; q < 4; ++q) {
        float p = 0.f;
        #pragma unroll
        for (int nf = 0; nf < 8; ++nf) p += fast_tanh(acc[nf][q] + b1v[nf]) * w2v[nf];
        p += __shfl_xor(p, 1); p += __shfl_xor(p, 2);
        p += __shfl_xor(p, 4); p += __shfl_xor(p, 8);
        if (r == 0) e[i0 + w * 16 + g * 4 + q] = __expf(p + b2v);  // |s| small: no max shift
    }
}

// ---------------- pool weighted partial sums: 16 rows per block ----------------
__global__ __launch_bounds__(256) void k_pool_wsum(const float* __restrict__ xsrc,
                                                   const float* __restrict__ e,
                                                   float* __restrict__ part) {
    int b = blockIdx.x, ch = blockIdx.y, c = threadIdx.x;
    __shared__ float el[16];
    int n0 = ch * 16;
    if (c < 16) el[c] = e[b * N_ + n0 + c];
    __syncthreads();
    const float* xp = xsrc + (long long)(b * N_ + n0) * HID_ + c;
    float acc = 0.f;
    #pragma unroll
    for (int n = 0; n < 16; ++n) acc += el[n] * xp[n * HID_];
    part[(b * 128 + ch) * HID_ + c] = acc;
}

// ---------------- pool final reduce: Z from e, sum 128 partials ----------------
__global__ __launch_bounds__(256) void k_pool_final(const float* __restrict__ part,
                                                    const float* __restrict__ e,
                                                    float* __restrict__ out) {
    int b = blockIdx.x, c = threadIdx.x;
    int lane = c & 63, w = c >> 6;
    float z = 0.f;
    #pragma unroll
    for (int k = 0; k < 8; ++k) z += e[b * N_ + c + k * 256];
    #pragma unroll
    for (int o = 1; o < 64; o <<= 1) z += __shfl_xor(z, o);
    __shared__ float red[4];
    if (lane == 0) red[w] = z;
    __syncthreads();
    float Z = red[0] + red[1] + red[2] + red[3];
    float acc = 0.f;
    #pragma unroll 8
    for (int ch = 0; ch < 128; ++ch) acc += part[(b * 128 + ch) * HID_ + c];
    out[b * HID_ + c] = acc / Z;
}

extern "C" void kernel_launch(void* const* d_in, const int* in_sizes, int n_in,
                              void* d_out, int out_size, void* d_ws, size_t ws_size,
                              hipStream_t stream) {
    const float* ge     = (const float*)d_in[0];
    const int*   adj    = (const int*)d_in[1];
    const float* in_w   = (const float*)d_in[2];
    const float* in_b   = (const float*)d_in[3];
    const float* proj_w = (const float*)d_in[4];
    const float* a_src  = (const float*)d_in[5];
    const float* a_dst  = (const float*)d_in[6];
    const float* pw1    = (const float*)d_in[7];
    const float* pb1    = (const float*)d_in[8];
    const float* pw2    = (const float*)d_in[9];
    const float* pb2    = (const float*)d_in[10];
    const float* ipw1   = (const float*)d_in[11];
    const float* ipb1   = (const float*)d_in[12];
    const float* ipw2   = (const float*)d_in[13];
    const float* ipb2   = (const float*)d_in[14];

    char* ws = (char*)d_ws;
    float*    x     = (float*)(ws + 0);            // 4 MB
    bf16*     xb    = (bf16*)(ws + 4194304);       // 2 MB
    bf16*     hbT   = (bf16*)(ws + 6291456);       // 2 MB
    float*    sp    = (float*)(ws + 8388608);      // 16 KB
    float*    srcM  = (float*)(ws + 8404992);      // 64 KB
    float*    dstT  = (float*)(ws + 8470528);      // 64 KB
    unsigned* am    = (unsigned*)(ws + 8536064);   // 1 MB
    bf16*     wT0   = (bf16*)(ws + 9584640);       // 128 KB
    bf16*     wT1   = wT0 + 65536;                 // 128 KB
    bf16*     ipw1T = wT1 + 65536;                 // 64 KB
    bf16*     w1T0  = ipw1T + 32768;               // 64 KB
    bf16*     w1T1  = w1T0 + 32768;                // 64 KB
    float*    part  = (float*)(ws + 10043392);     // 256 KB

    float* outRaw = (float*)d_out;
    float* node0  = outRaw + 512;
    float* node1  = node0 + 1048576;
    float* pool0  = node1 + 1048576;
    float* pool1  = pool0 + 512;

    k_input_proj<<<B_ * N_, HID_, 0, stream>>>(ge, in_w, in_b, x, xb);
    k_adjbits<<<B_ * N_ * N_ / 256, 256, 0, stream>>>(adj, am);
    k_prep<<<896, 256, 0, stream>>>(proj_w, ipw1, pw1, wT0, wT1, ipw1T, w1T0, w1T1);

    // raw pool (on x)
    k_pool_score<<<64, 256, 0, stream>>>(xb, ipw1T, ipb1, ipw2, ipb2, sp);
    k_pool_wsum<<<dim3(B_, 128), 256, 0, stream>>>(x, sp, part);
    k_pool_final<<<B_, 256, 0, stream>>>(part, sp, outRaw);

    for (int l = 0; l < 2; ++l) {
        bf16* wT   = l ? wT1 : wT0;
        bf16* w1T  = l ? w1T1 : w1T0;
        float* node   = l ? node1 : node0;
        float* pooled = l ? pool1 : pool0;
        k_gemm_h<<<dim3(64, 4), 256, 0, stream>>>(xb, wT, a_src + l * 256, a_dst + l * 256,
                                                  hbT, srcM, dstT);
        k_attn<<<dim3(128, 4, 2), 512, 0, stream>>>(srcM, dstT, am, hbT, node, xb);
        k_pool_score<<<64, 256, 0, stream>>>(xb, w1T, pb1 + l * POOL_, pw2 + l * POOL_,
                                             pb2 + l, sp);
        k_pool_wsum<<<dim3(B_, 128), 256, 0, stream>>>(node, sp, part);
        k_pool_final<<<B_, 256, 0, stream>>>(part, sp, pooled);
    }
}

// Round 5
// 123.743 us; speedup vs baseline: 2.4970x; 1.3082x over previous
//
#include <hip/hip_runtime.h>
#include <hip/hip_bf16.h>

#define B_ 2
#define N_ 2048
#define HID_ 256
#define HEADS_ 4
#define D_ 64
#define POOL_ 128

typedef __bf16 bf16;
typedef __bf16 bf16x8 __attribute__((ext_vector_type(8)));
typedef float f32x4 __attribute__((ext_vector_type(4)));

__device__ __forceinline__ float fast_tanh(float x) {
    x = fminf(fmaxf(x, -15.f), 15.f);
    float t = __expf(2.f * x);
    return (t - 1.f) / (t + 1.f);
}

// ---------------- fused setup: adjbits + input proj + weight transposes ----------------
__global__ void k_setup(const int* __restrict__ adj, unsigned* __restrict__ am,
                        const float* __restrict__ ge, const float* __restrict__ iw,
                        const float* __restrict__ ib, bf16* __restrict__ xb,
                        const float* __restrict__ proj_w, const float* __restrict__ ipw1,
                        const float* __restrict__ pw1, bf16* __restrict__ wT0,
                        bf16* __restrict__ wT1, bf16* __restrict__ ipw1T,
                        bf16* __restrict__ w1T0, bf16* __restrict__ w1T1) {
    int blk = blockIdx.x, tid = threadIdx.x;
    if (blk < 32768) {
        // adjacency -> bitmask via ballot
        int gid = blk * 256 + tid;
        int v = adj[gid];
        unsigned long long mask = __ballot(v > 0);
        int lane = tid & 63;
        if (lane == 0) am[gid >> 5] = (unsigned)mask;
        else if (lane == 32) am[gid >> 5] = (unsigned)(mask >> 32);
    } else if (blk < 36864) {
        // input projection -> bf16 only
        int row = blk - 32768;
        float g = ge[row];
        float v = fmaxf(g * iw[tid] + ib[tid], 0.f);
        xb[row * HID_ + tid] = (bf16)v;
    } else {
        // weight transposes: f32 [256][Nc] -> bf16 [Nc][256]
        int o = (blk - 36864) * 256 + tid;
        const float* src; bf16* dst; int Nc, loc;
        if (o < 65536)       { src = proj_w;         dst = wT0;   Nc = 256; loc = o; }
        else if (o < 131072) { src = proj_w + 65536; dst = wT1;   Nc = 256; loc = o - 65536; }
        else if (o < 163840) { src = ipw1;           dst = ipw1T; Nc = 128; loc = o - 131072; }
        else if (o < 196608) { src = pw1;            dst = w1T0;  Nc = 128; loc = o - 163840; }
        else                 { src = pw1 + 32768;    dst = w1T1;  Nc = 128; loc = o - 196608; }
        int n = loc >> 8, k = loc & 255;
        dst[loc] = (bf16)src[k * Nc + n];
    }
}

// ---------------- h = xb @ W (per head); epilogue: src/dst dots + LDS-transposed hbT ----------------
__global__ __launch_bounds__(256) void k_gemm_h(const bf16* __restrict__ A,
                                                const bf16* __restrict__ WT,
                                                const float* __restrict__ as,
                                                const float* __restrict__ ad,
                                                bf16* __restrict__ hbT,
                                                float* __restrict__ srcM,
                                                float* __restrict__ dstT) {
    int i0 = blockIdx.x * 64, hd = blockIdx.y;
    int n0 = hd * 64;
    int w = threadIdx.x >> 6, lane = threadIdx.x & 63, r = lane & 15, g = lane >> 4;
    const bf16* ap = A + (i0 + w * 16 + r) * 256 + g * 8;
    f32x4 acc[4] = {{0,0,0,0},{0,0,0,0},{0,0,0,0},{0,0,0,0}};
    for (int ks = 0; ks < 256; ks += 32) {
        bf16x8 af = *(const bf16x8*)(ap + ks);
        #pragma unroll
        for (int nf = 0; nf < 4; ++nf) {
            bf16x8 bfr = *(const bf16x8*)(WT + (n0 + nf * 16 + r) * 256 + ks + g * 8);
            acc[nf] = __builtin_amdgcn_mfma_f32_16x16x32_bf16(af, bfr, acc[nf], 0, 0, 0);
        }
    }
    int b = i0 >> 11, nbase = i0 & 2047;
    int bh = b * HEADS_ + hd;
    float asv[4], adv[4];
    #pragma unroll
    for (int nf = 0; nf < 4; ++nf) {
        asv[nf] = as[hd * 64 + nf * 16 + r];
        adv[nf] = ad[hd * 64 + nf * 16 + r];
    }
    __shared__ float tr[64][65];
    #pragma unroll
    for (int q = 0; q < 4; ++q) {
        int ln = w * 16 + g * 4 + q;
        float ps = 0.f, pd = 0.f;
        #pragma unroll
        for (int nf = 0; nf < 4; ++nf) {
            float v = acc[nf][q];
            ps += v * asv[nf];
            pd += v * adv[nf];
            tr[nf * 16 + r][ln] = v;
        }
        ps += __shfl_xor(ps, 1); ps += __shfl_xor(ps, 2);
        ps += __shfl_xor(ps, 4); ps += __shfl_xor(ps, 8);
        pd += __shfl_xor(pd, 1); pd += __shfl_xor(pd, 2);
        pd += __shfl_xor(pd, 4); pd += __shfl_xor(pd, 8);
        if (r == 0) {
            srcM[bh * N_ + nbase + ln] = ps;
            dstT[bh * N_ + nbase + ln] = pd;
        }
    }
    __syncthreads();
    // coalesced hbT write: [bh][d][n]
    int ld = threadIdx.x >> 2, ln0 = (threadIdx.x & 3) * 16;
    bf16x8 o0, o1;
    #pragma unroll
    for (int e = 0; e < 8; ++e) {
        o0[e] = (bf16)tr[ld][ln0 + e];
        o1[e] = (bf16)tr[ld][ln0 + 8 + e];
    }
    bf16* hp = hbT + ((long long)bh * D_ + ld) * N_ + nbase + ln0;
    *(bf16x8*)(hp) = o0;
    *(bf16x8*)(hp + 8) = o1;
}

// ---------------- fused GAT attention v5: QBLK=32, LDS-tiled V, reg prefetch ----------------
__global__ __launch_bounds__(512, 4) void k_attn(const float* __restrict__ srcM,
                                                 const float* __restrict__ dstT,
                                                 const unsigned* __restrict__ am,
                                                 const bf16* __restrict__ hbT,
                                                 float* __restrict__ nodeOut,
                                                 bf16* __restrict__ xbNext) {
    int it = blockIdx.x, hd = blockIdx.y, b = blockIdx.z;
    int i0 = it * 32;
    int tid = threadIdx.x;
    int w = tid >> 6, lane = tid & 63, r = lane & 15, g = lane >> 4;
    int rg = w >> 2, wj = w & 3;          // rowgroup (2x16 rows), j-slice (4x64 j per tile)
    int bh = b * HEADS_ + hd;
    const float* drow = dstT + bh * N_;
    const bf16* vbase = hbT + (long long)bh * D_ * N_;

    // vtile [64][264] bf16 (33792 B) aliased with epilogue accs [8][16][68] f32 (34816 B)
    __shared__ __align__(16) char smem[34816];
    bf16* vt = (bf16*)smem;
    float (*accs)[16][68] = (float (*)[16][68])smem;
    __shared__ float lred[8][16];

    int i = i0 + rg * 16 + r;
    const unsigned* mrow = am + ((long long)(b * N_ + i)) * 64;
    float sv = srcM[bh * N_ + i];

    f32x4 acc[4] = {{0,0,0,0},{0,0,0,0},{0,0,0,0},{0,0,0,0}};
    float l = 0.f;

    // prefetch tile 0 into registers
    bf16x8 st[4];
    #pragma unroll
    for (int k = 0; k < 4; ++k) {
        int s = tid + k * 512, d = s >> 5, seg = s & 31;
        st[k] = *(const bf16x8*)(vbase + d * N_ + seg * 8);
    }

    #pragma unroll
    for (int t = 0; t < 8; ++t) {
        #pragma unroll
        for (int k = 0; k < 4; ++k) {
            int s = tid + k * 512, d = s >> 5, seg = s & 31;
            *(bf16x8*)(vt + d * 264 + seg * 8) = st[k];
        }
        __syncthreads();
        if (t < 7) {
            #pragma unroll
            for (int k = 0; k < 4; ++k) {
                int s = tid + k * 512, d = s >> 5, seg = s & 31;
                st[k] = *(const bf16x8*)(vbase + d * N_ + (t + 1) * 256 + seg * 8);
            }
        }
        #pragma unroll
        for (int s = 0; s < 2; ++s) {
            int jb = t * 256 + wj * 64 + s * 32 + g * 8;
            float4 dv0 = *(const float4*)(drow + jb);
            float4 dv1 = *(const float4*)(drow + jb + 4);
            unsigned mb = (mrow[t * 8 + wj * 2 + s] >> (g * 8)) & 0xFFu;
            float dd[8] = {dv0.x, dv0.y, dv0.z, dv0.w, dv1.x, dv1.y, dv1.z, dv1.w};
            bf16x8 af;
            float es[8];
            #pragma unroll
            for (int tt = 0; tt < 8; ++tt) {
                float s2 = sv + dd[tt];
                float lv = fmaxf(s2, 0.2f * s2);      // leaky_relu(0.2); exp safe unshifted
                float e2 = __expf(lv);
                e2 = ((mb >> tt) & 1u) ? e2 : 0.f;
                es[tt] = e2;
                af[tt] = (bf16)e2;
            }
            l += ((es[0] + es[1]) + (es[2] + es[3])) + ((es[4] + es[5]) + (es[6] + es[7]));
            #pragma unroll
            for (int nf = 0; nf < 4; ++nf) {
                bf16x8 vf = *(const bf16x8*)(vt + (nf * 16 + r) * 264 + wj * 64 + s * 32 + g * 8);
                acc[nf] = __builtin_amdgcn_mfma_f32_16x16x32_bf16(af, vf, acc[nf], 0, 0, 0);
            }
        }
        __syncthreads();
    }

    // combine g-groups within wave (disjoint j), then across the 4 waves of each rowgroup
    l += __shfl_xor(l, 16);
    l += __shfl_xor(l, 32);
    if (g == 0) lred[w][r] = l;
    #pragma unroll
    for (int nf = 0; nf < 4; ++nf)
        #pragma unroll
        for (int q = 0; q < 4; ++q)
            accs[w][g * 4 + q][nf * 16 + r] = acc[nf][q];
    __syncthreads();

    int cc = lane;
    #pragma unroll
    for (int k = 0; k < 4; ++k) {
        int rr = w * 4 + k;                 // 0..31
        int rg2 = rr >> 4, rl = rr & 15;
        float ls = 0.f, v = 0.f;
        #pragma unroll
        for (int w2 = 0; w2 < 4; ++w2) {
            ls += lred[rg2 * 4 + w2][rl];
            v += accs[rg2 * 4 + w2][rl][cc];
        }
        v /= ls;
        float o = v > 0.f ? v : expm1f(v);  // elu
        int idx = (b * N_ + i0 + rr) * HID_ + hd * D_ + cc;
        nodeOut[idx] = o;
        xbNext[idx] = (bf16)o;
    }
}

// ---------------- fused pool: score GEMM + exp + weighted partial sum (16 rows/block) ----------------
__global__ __launch_bounds__(256) void k_pool_sw(const bf16* __restrict__ A,
                                                 const bf16* __restrict__ W1T,
                                                 const float* __restrict__ b1,
                                                 const float* __restrict__ w2,
                                                 const float* __restrict__ b2,
                                                 float* __restrict__ part,
                                                 float* __restrict__ pz) {
    int ch = blockIdx.x, b = blockIdx.y;
    int n0 = ch * 16;
    int tid = threadIdx.x;
    int w = tid >> 6, lane = tid & 63, r = lane & 15, g = lane >> 4;
    // wave w: pool cols w*32..w*32+31 (nf 0..1), all 16 rows
    const bf16* ap = A + ((long long)(b * N_ + n0) + r) * 256 + g * 8;
    f32x4 acc[2] = {{0,0,0,0},{0,0,0,0}};
    for (int ks = 0; ks < 256; ks += 32) {
        bf16x8 af = *(const bf16x8*)(ap + ks);
        #pragma unroll
        for (int nf = 0; nf < 2; ++nf) {
            bf16x8 bfr = *(const bf16x8*)(W1T + (w * 32 + nf * 16 + r) * 256 + ks + g * 8);
            acc[nf] = __builtin_amdgcn_mfma_f32_16x16x32_bf16(af, bfr, acc[nf], 0, 0, 0);
        }
    }
    float b1v[2], w2v[2];
    #pragma unroll
    for (int nf = 0; nf < 2; ++nf) {
        b1v[nf] = b1[w * 32 + nf * 16 + r];
        w2v[nf] = w2[w * 32 + nf * 16 + r];
    }
    __shared__ float pred[4][16];
    __shared__ float el[16];
    #pragma unroll
    for (int q = 0; q < 4; ++q) {
        float p = fast_tanh(acc[0][q] + b1v[0]) * w2v[0] + fast_tanh(acc[1][q] + b1v[1]) * w2v[1];
        p += __shfl_xor(p, 1); p += __shfl_xor(p, 2);
        p += __shfl_xor(p, 4); p += __shfl_xor(p, 8);
        if (r == 0) pred[w][g * 4 + q] = p;
    }
    __syncthreads();
    if (tid < 16) {
        float s = pred[0][tid] + pred[1][tid] + pred[2][tid] + pred[3][tid] + b2[0];
        el[tid] = __expf(s);                 // |s| small: no max shift needed
    }
    __syncthreads();
    if (tid == 0) {
        float z = 0.f;
        #pragma unroll
        for (int n = 0; n < 16; ++n) z += el[n];
        pz[b * 128 + ch] = z;
    }
    // weighted partial sum over the 16 rows, bf16 source
    const bf16* xp = A + (long long)(b * N_ + n0) * 256 + tid;
    float accum = 0.f;
    #pragma unroll
    for (int n = 0; n < 16; ++n) accum += el[n] * (float)xp[n * 256];
    part[((long long)b * 128 + ch) * 256 + tid] = accum;
}

// ---------------- pool final: Z and sum of 128 partials ----------------
__global__ __launch_bounds__(256) void k_pool_final(const float* __restrict__ part,
                                                    const float* __restrict__ pz,
                                                    float* __restrict__ out) {
    int b = blockIdx.x, tid = threadIdx.x;
    int lane = tid & 63, w = tid >> 6;
    float z = (tid < 128) ? pz[b * 128 + tid] : 0.f;
    #pragma unroll
    for (int o = 1; o < 64; o <<= 1) z += __shfl_xor(z, o);
    __shared__ float red[4];
    if (lane == 0) red[w] = z;
    __syncthreads();
    float Z = red[0] + red[1] + red[2] + red[3];
    float acc = 0.f;
    #pragma unroll 8
    for (int ch = 0; ch < 128; ++ch) acc += part[((long long)b * 128 + ch) * 256 + tid];
    out[b * HID_ + tid] = acc / Z;
}

extern "C" void kernel_launch(void* const* d_in, const int* in_sizes, int n_in,
                              void* d_out, int out_size, void* d_ws, size_t ws_size,
                              hipStream_t stream) {
    const float* ge     = (const float*)d_in[0];
    const int*   adj    = (const int*)d_in[1];
    const float* in_w   = (const float*)d_in[2];
    const float* in_b   = (const float*)d_in[3];
    const float* proj_w = (const float*)d_in[4];
    const float* a_src  = (const float*)d_in[5];
    const float* a_dst  = (const float*)d_in[6];
    const float* pw1    = (const float*)d_in[7];
    const float* pb1    = (const float*)d_in[8];
    const float* pw2    = (const float*)d_in[9];
    const float* pb2    = (const float*)d_in[10];
    const float* ipw1   = (const float*)d_in[11];
    const float* ipb1   = (const float*)d_in[12];
    const float* ipw2   = (const float*)d_in[13];
    const float* ipb2   = (const float*)d_in[14];

    char* ws = (char*)d_ws;
    bf16*     xb    = (bf16*)(ws + 0);             // 2 MB
    bf16*     hbT   = (bf16*)(ws + 2097152);       // 2 MB
    float*    srcM  = (float*)(ws + 4194304);      // 64 KB
    float*    dstT  = (float*)(ws + 4259840);      // 64 KB
    unsigned* am    = (unsigned*)(ws + 4325376);   // 1 MB
    bf16*     wT0   = (bf16*)(ws + 5373952);       // 128 KB
    bf16*     wT1   = wT0 + 65536;                 // 128 KB
    bf16*     ipw1T = wT1 + 65536;                 // 64 KB
    bf16*     w1T0  = ipw1T + 32768;               // 64 KB
    bf16*     w1T1  = w1T0 + 32768;                // 64 KB
    float*    part  = (float*)(ws + 5832704);      // 256 KB
    float*    pz    = (float*)(ws + 6094848);      // 1 KB

    float* outRaw = (float*)d_out;
    float* node0  = outRaw + 512;
    float* node1  = node0 + 1048576;
    float* pool0  = node1 + 1048576;
    float* pool1  = pool0 + 512;

    k_setup<<<37760, 256, 0, stream>>>(adj, am, ge, in_w, in_b, xb,
                                       proj_w, ipw1, pw1, wT0, wT1, ipw1T, w1T0, w1T1);

    // raw pool (on xb, before layer 0 overwrites it)
    k_pool_sw<<<dim3(128, B_), 256, 0, stream>>>(xb, ipw1T, ipb1, ipw2, ipb2, part, pz);
    k_pool_final<<<B_, 256, 0, stream>>>(part, pz, outRaw);

    for (int l = 0; l < 2; ++l) {
        bf16* wT   = l ? wT1 : wT0;
        bf16* w1T  = l ? w1T1 : w1T0;
        float* node   = l ? node1 : node0;
        float* pooled = l ? pool1 : pool0;
        k_gemm_h<<<dim3(64, 4), 256, 0, stream>>>(xb, wT, a_src + l * 256, a_dst + l * 256,
                                                  hbT, srcM, dstT);
        k_attn<<<dim3(64, 4, 2), 512, 0, stream>>>(srcM, dstT, am, hbT, node, xb);
        k_pool_sw<<<dim3(128, B_), 256, 0, stream>>>(xb, w1T, pb1 + l * POOL_,
                                                     pw2 + l * POOL_, pb2 + l, part, pz);
        k_pool_final<<<B_, 256, 0, stream>>>(part, pz, pooled);
    }
}

// Round 6
// 104.998 us; speedup vs baseline: 2.9428x; 1.1785x over previous
//
#include <hip/hip_runtime.h>
#include <hip/hip_bf16.h>

#define B_ 2
#define N_ 2048
#define HID_ 256
#define HEADS_ 4
#define D_ 64
#define POOL_ 128

typedef __bf16 bf16;
typedef __bf16 bf16x8 __attribute__((ext_vector_type(8)));
typedef float f32x4 __attribute__((ext_vector_type(4)));

__device__ __forceinline__ float fast_tanh(float x) {
    x = fminf(fmaxf(x, -15.f), 15.f);
    float t = __expf(2.f * x);
    return (t - 1.f) / (t + 1.f);
}

// ---------------- fused setup: adjbits + input proj + weight transposes ----------------
__global__ void k_setup(const int* __restrict__ adj, unsigned* __restrict__ am,
                        const float* __restrict__ ge, const float* __restrict__ iw,
                        const float* __restrict__ ib, bf16* __restrict__ xb,
                        const float* __restrict__ proj_w, const float* __restrict__ ipw1,
                        const float* __restrict__ pw1, bf16* __restrict__ wT0,
                        bf16* __restrict__ wT1, bf16* __restrict__ ipw1T,
                        bf16* __restrict__ w1T0, bf16* __restrict__ w1T1) {
    int blk = blockIdx.x, tid = threadIdx.x;
    if (blk < 32768) {
        // adjacency -> bitmask via ballot
        int gid = blk * 256 + tid;
        int v = adj[gid];
        unsigned long long mask = __ballot(v > 0);
        int lane = tid & 63;
        if (lane == 0) am[gid >> 5] = (unsigned)mask;
        else if (lane == 32) am[gid >> 5] = (unsigned)(mask >> 32);
    } else if (blk < 36864) {
        // input projection -> bf16 only
        int row = blk - 32768;
        float g = ge[row];
        float v = fmaxf(g * iw[tid] + ib[tid], 0.f);
        xb[row * HID_ + tid] = (bf16)v;
    } else {
        // weight transposes: f32 [256][Nc] -> bf16 [Nc][256]
        int o = (blk - 36864) * 256 + tid;
        const float* src; bf16* dst; int Nc, loc;
        if (o < 65536)       { src = proj_w;         dst = wT0;   Nc = 256; loc = o; }
        else if (o < 131072) { src = proj_w + 65536; dst = wT1;   Nc = 256; loc = o - 65536; }
        else if (o < 163840) { src = ipw1;           dst = ipw1T; Nc = 128; loc = o - 131072; }
        else if (o < 196608) { src = pw1;            dst = w1T0;  Nc = 128; loc = o - 163840; }
        else                 { src = pw1 + 32768;    dst = w1T1;  Nc = 128; loc = o - 196608; }
        int n = loc >> 8, k = loc & 255;
        dst[loc] = (bf16)src[k * Nc + n];
    }
}

// ---------------- pool partial body: score GEMM + exp + weighted partial sum ----------------
__device__ __forceinline__ void pool_sw_body(const bf16* __restrict__ A,
                                             const bf16* __restrict__ W1T,
                                             const float* __restrict__ b1,
                                             const float* __restrict__ w2,
                                             const float* __restrict__ b2,
                                             float* __restrict__ part,
                                             float* __restrict__ pz,
                                             int slot, int b, int ch, char* smemraw) {
    int n0 = ch * 16;
    int tid = threadIdx.x;
    int w = tid >> 6, lane = tid & 63, r = lane & 15, g = lane >> 4;
    const bf16* ap = A + ((long long)(b * N_ + n0) + r) * 256 + g * 8;
    f32x4 acc[2] = {{0,0,0,0},{0,0,0,0}};
    for (int ks = 0; ks < 256; ks += 32) {
        bf16x8 af = *(const bf16x8*)(ap + ks);
        #pragma unroll
        for (int nf = 0; nf < 2; ++nf) {
            bf16x8 bfr = *(const bf16x8*)(W1T + (w * 32 + nf * 16 + r) * 256 + ks + g * 8);
            acc[nf] = __builtin_amdgcn_mfma_f32_16x16x32_bf16(af, bfr, acc[nf], 0, 0, 0);
        }
    }
    float b1v[2], w2v[2];
    #pragma unroll
    for (int nf = 0; nf < 2; ++nf) {
        b1v[nf] = b1[w * 32 + nf * 16 + r];
        w2v[nf] = w2[w * 32 + nf * 16 + r];
    }
    float (*pred)[16] = (float (*)[16])smemraw;          // [4][16]
    float* el = (float*)(smemraw + 256);                 // [16]
    #pragma unroll
    for (int q = 0; q < 4; ++q) {
        float p = fast_tanh(acc[0][q] + b1v[0]) * w2v[0] + fast_tanh(acc[1][q] + b1v[1]) * w2v[1];
        p += __shfl_xor(p, 1); p += __shfl_xor(p, 2);
        p += __shfl_xor(p, 4); p += __shfl_xor(p, 8);
        if (r == 0) pred[w][g * 4 + q] = p;
    }
    __syncthreads();
    if (tid < 16) {
        float s = pred[0][tid] + pred[1][tid] + pred[2][tid] + pred[3][tid] + b2[0];
        el[tid] = __expf(s);                 // |s| small: no max shift needed
    }
    __syncthreads();
    if (tid == 0) {
        float z = 0.f;
        #pragma unroll
        for (int n = 0; n < 16; ++n) z += el[n];
        pz[(slot * B_ + b) * 128 + ch] = z;
    }
    const bf16* xp = A + (long long)(b * N_ + n0) * 256 + tid;
    float accum = 0.f;
    #pragma unroll
    for (int n = 0; n < 16; ++n) accum += el[n] * (float)xp[n * 256];
    part[(((long long)slot * B_ + b) * 128 + ch) * 256 + tid] = accum;
}

// ---------------- merged: gemm_h (blocks 0-255) + pool partials (blocks 256-511) ----------------
__global__ __launch_bounds__(256) void k_gemm_h_pool(const bf16* __restrict__ A,
                                                     const bf16* __restrict__ WT,
                                                     const float* __restrict__ as,
                                                     const float* __restrict__ ad,
                                                     bf16* __restrict__ hbT,
                                                     float* __restrict__ srcM,
                                                     float* __restrict__ dstT,
                                                     const bf16* __restrict__ W1T,
                                                     const float* __restrict__ b1,
                                                     const float* __restrict__ w2,
                                                     const float* __restrict__ b2,
                                                     float* __restrict__ part,
                                                     float* __restrict__ pz, int slot) {
    __shared__ __align__(16) char smem[16640];           // tr[64][65] f32 / pool scratch
    int blk = blockIdx.x;
    if (blk >= 256) {
        int pb = blk - 256;
        pool_sw_body(A, W1T, b1, w2, b2, part, pz, slot, pb >> 7, pb & 127, smem);
        return;
    }
    int i0 = (blk & 63) * 64, hd = blk >> 6;
    int n0 = hd * 64;
    int w = threadIdx.x >> 6, lane = threadIdx.x & 63, r = lane & 15, g = lane >> 4;
    const bf16* ap = A + (i0 + w * 16 + r) * 256 + g * 8;
    f32x4 acc[4] = {{0,0,0,0},{0,0,0,0},{0,0,0,0},{0,0,0,0}};
    for (int ks = 0; ks < 256; ks += 32) {
        bf16x8 af = *(const bf16x8*)(ap + ks);
        #pragma unroll
        for (int nf = 0; nf < 4; ++nf) {
            bf16x8 bfr = *(const bf16x8*)(WT + (n0 + nf * 16 + r) * 256 + ks + g * 8);
            acc[nf] = __builtin_amdgcn_mfma_f32_16x16x32_bf16(af, bfr, acc[nf], 0, 0, 0);
        }
    }
    int b = i0 >> 11, nbase = i0 & 2047;
    int bh = b * HEADS_ + hd;
    float asv[4], adv[4];
    #pragma unroll
    for (int nf = 0; nf < 4; ++nf) {
        asv[nf] = as[hd * 64 + nf * 16 + r];
        adv[nf] = ad[hd * 64 + nf * 16 + r];
    }
    float (*tr)[65] = (float (*)[65])smem;
    #pragma unroll
    for (int q = 0; q < 4; ++q) {
        int ln = w * 16 + g * 4 + q;
        float ps = 0.f, pd = 0.f;
        #pragma unroll
        for (int nf = 0; nf < 4; ++nf) {
            float v = acc[nf][q];
            ps += v * asv[nf];
            pd += v * adv[nf];
            tr[nf * 16 + r][ln] = v;
        }
        ps += __shfl_xor(ps, 1); ps += __shfl_xor(ps, 2);
        ps += __shfl_xor(ps, 4); ps += __shfl_xor(ps, 8);
        pd += __shfl_xor(pd, 1); pd += __shfl_xor(pd, 2);
        pd += __shfl_xor(pd, 4); pd += __shfl_xor(pd, 8);
        if (r == 0) {
            srcM[bh * N_ + nbase + ln] = ps;
            dstT[bh * N_ + nbase + ln] = pd;
        }
    }
    __syncthreads();
    // coalesced hbT write: [bh][d][n]
    int ld = threadIdx.x >> 2, ln0 = (threadIdx.x & 3) * 16;
    bf16x8 o0, o1;
    #pragma unroll
    for (int e = 0; e < 8; ++e) {
        o0[e] = (bf16)tr[ld][ln0 + e];
        o1[e] = (bf16)tr[ld][ln0 + 8 + e];
    }
    bf16* hp = hbT + ((long long)bh * D_ + ld) * N_ + nbase + ln0;
    *(bf16x8*)(hp) = o0;
    *(bf16x8*)(hp + 8) = o1;
}

// ---------------- standalone pool partials (for the last pool) ----------------
__global__ __launch_bounds__(256) void k_pool_sw(const bf16* __restrict__ A,
                                                 const bf16* __restrict__ W1T,
                                                 const float* __restrict__ b1,
                                                 const float* __restrict__ w2,
                                                 const float* __restrict__ b2,
                                                 float* __restrict__ part,
                                                 float* __restrict__ pz, int slot) {
    __shared__ __align__(16) char smem[320];
    pool_sw_body(A, W1T, b1, w2, b2, part, pz, slot, blockIdx.y, blockIdx.x, smem);
}

// ---------------- fused GAT attention v5: QBLK=32, LDS-tiled V, reg prefetch ----------------
__global__ __launch_bounds__(512, 4) void k_attn(const float* __restrict__ srcM,
                                                 const float* __restrict__ dstT,
                                                 const unsigned* __restrict__ am,
                                                 const bf16* __restrict__ hbT,
                                                 float* __restrict__ nodeOut,
                                                 bf16* __restrict__ xbNext) {
    int it = blockIdx.x, hd = blockIdx.y, b = blockIdx.z;
    int i0 = it * 32;
    int tid = threadIdx.x;
    int w = tid >> 6, lane = tid & 63, r = lane & 15, g = lane >> 4;
    int rg = w >> 2, wj = w & 3;          // rowgroup (2x16 rows), j-slice (4x64 j per tile)
    int bh = b * HEADS_ + hd;
    const float* drow = dstT + bh * N_;
    const bf16* vbase = hbT + (long long)bh * D_ * N_;

    // vtile [64][264] bf16 (33792 B) aliased with epilogue accs [8][16][68] f32 (34816 B)
    __shared__ __align__(16) char smem[34816];
    bf16* vt = (bf16*)smem;
    float (*accs)[16][68] = (float (*)[16][68])smem;
    __shared__ float lred[8][16];

    int i = i0 + rg * 16 + r;
    const unsigned* mrow = am + ((long long)(b * N_ + i)) * 64;
    float sv = srcM[bh * N_ + i];

    f32x4 acc[4] = {{0,0,0,0},{0,0,0,0},{0,0,0,0},{0,0,0,0}};
    float l = 0.f;

    // prefetch tile 0 into registers
    bf16x8 st[4];
    #pragma unroll
    for (int k = 0; k < 4; ++k) {
        int s = tid + k * 512, d = s >> 5, seg = s & 31;
        st[k] = *(const bf16x8*)(vbase + d * N_ + seg * 8);
    }

    #pragma unroll
    for (int t = 0; t < 8; ++t) {
        #pragma unroll
        for (int k = 0; k < 4; ++k) {
            int s = tid + k * 512, d = s >> 5, seg = s & 31;
            *(bf16x8*)(vt + d * 264 + seg * 8) = st[k];
        }
        __syncthreads();
        if (t < 7) {
            #pragma unroll
            for (int k = 0; k < 4; ++k) {
                int s = tid + k * 512, d = s >> 5, seg = s & 31;
                st[k] = *(const bf16x8*)(vbase + d * N_ + (t + 1) * 256 + seg * 8);
            }
        }
        #pragma unroll
        for (int s = 0; s < 2; ++s) {
            int jb = t * 256 + wj * 64 + s * 32 + g * 8;
            float4 dv0 = *(const float4*)(drow + jb);
            float4 dv1 = *(const float4*)(drow + jb + 4);
            unsigned mb = (mrow[t * 8 + wj * 2 + s] >> (g * 8)) & 0xFFu;
            float dd[8] = {dv0.x, dv0.y, dv0.z, dv0.w, dv1.x, dv1.y, dv1.z, dv1.w};
            bf16x8 af;
            float es[8];
            #pragma unroll
            for (int tt = 0; tt < 8; ++tt) {
                float s2 = sv + dd[tt];
                float lv = fmaxf(s2, 0.2f * s2);      // leaky_relu(0.2); exp safe unshifted
                float e2 = __expf(lv);
                e2 = ((mb >> tt) & 1u) ? e2 : 0.f;
                es[tt] = e2;
                af[tt] = (bf16)e2;
            }
            l += ((es[0] + es[1]) + (es[2] + es[3])) + ((es[4] + es[5]) + (es[6] + es[7]));
            #pragma unroll
            for (int nf = 0; nf < 4; ++nf) {
                bf16x8 vf = *(const bf16x8*)(vt + (nf * 16 + r) * 264 + wj * 64 + s * 32 + g * 8);
                acc[nf] = __builtin_amdgcn_mfma_f32_16x16x32_bf16(af, vf, acc[nf], 0, 0, 0);
            }
        }
        __syncthreads();
    }

    // combine g-groups within wave (disjoint j), then across the 4 waves of each rowgroup
    l += __shfl_xor(l, 16);
    l += __shfl_xor(l, 32);
    if (g == 0) lred[w][r] = l;
    #pragma unroll
    for (int nf = 0; nf < 4; ++nf)
        #pragma unroll
        for (int q = 0; q < 4; ++q)
            accs[w][g * 4 + q][nf * 16 + r] = acc[nf][q];
    __syncthreads();

    int cc = lane;
    #pragma unroll
    for (int k = 0; k < 4; ++k) {
        int rr = w * 4 + k;                 // 0..31
        int rg2 = rr >> 4, rl = rr & 15;
        float ls = 0.f, v = 0.f;
        #pragma unroll
        for (int w2 = 0; w2 < 4; ++w2) {
            ls += lred[rg2 * 4 + w2][rl];
            v += accs[rg2 * 4 + w2][rl][cc];
        }
        v /= ls;
        float o = v > 0.f ? v : expm1f(v);  // elu
        int idx = (b * N_ + i0 + rr) * HID_ + hd * D_ + cc;
        nodeOut[idx] = o;
        xbNext[idx] = (bf16)o;
    }
}

// ---------------- all pool finals in one launch: grid (slot*B + b) ----------------
__global__ __launch_bounds__(256) void k_pool_finals(const float* __restrict__ part,
                                                     const float* __restrict__ pz,
                                                     float* __restrict__ outRaw,
                                                     float* __restrict__ pool0,
                                                     float* __restrict__ pool1) {
    int slot = blockIdx.x >> 1, b = blockIdx.x & 1;
    int tid = threadIdx.x;
    int lane = tid & 63, w = tid >> 6;
    float z = (tid < 128) ? pz[(slot * B_ + b) * 128 + tid] : 0.f;
    #pragma unroll
    for (int o = 1; o < 64; o <<= 1) z += __shfl_xor(z, o);
    __shared__ float red[4];
    if (lane == 0) red[w] = z;
    __syncthreads();
    float Z = red[0] + red[1] + red[2] + red[3];
    float acc = 0.f;
    #pragma unroll 8
    for (int ch = 0; ch < 128; ++ch)
        acc += part[(((long long)slot * B_ + b) * 128 + ch) * 256 + tid];
    float* out = slot == 0 ? outRaw : (slot == 1 ? pool0 : pool1);
    out[b * HID_ + tid] = acc / Z;
}

extern "C" void kernel_launch(void* const* d_in, const int* in_sizes, int n_in,
                              void* d_out, int out_size, void* d_ws, size_t ws_size,
                              hipStream_t stream) {
    const float* ge     = (const float*)d_in[0];
    const int*   adj    = (const int*)d_in[1];
    const float* in_w   = (const float*)d_in[2];
    const float* in_b   = (const float*)d_in[3];
    const float* proj_w = (const float*)d_in[4];
    const float* a_src  = (const float*)d_in[5];
    const float* a_dst  = (const float*)d_in[6];
    const float* pw1    = (const float*)d_in[7];
    const float* pb1    = (const float*)d_in[8];
    const float* pw2    = (const float*)d_in[9];
    const float* pb2    = (const float*)d_in[10];
    const float* ipw1   = (const float*)d_in[11];
    const float* ipb1   = (const float*)d_in[12];
    const float* ipw2   = (const float*)d_in[13];
    const float* ipb2   = (const float*)d_in[14];

    char* ws = (char*)d_ws;
    bf16*     xb    = (bf16*)(ws + 0);             // 2 MB
    bf16*     hbT   = (bf16*)(ws + 2097152);       // 2 MB
    float*    srcM  = (float*)(ws + 4194304);      // 64 KB
    float*    dstT  = (float*)(ws + 4259840);      // 64 KB
    unsigned* am    = (unsigned*)(ws + 4325376);   // 1 MB
    bf16*     wT0   = (bf16*)(ws + 5373952);       // 128 KB
    bf16*     wT1   = wT0 + 65536;                 // 128 KB
    bf16*     ipw1T = wT1 + 65536;                 // 64 KB
    bf16*     w1T0  = ipw1T + 32768;               // 64 KB
    bf16*     w1T1  = w1T0 + 32768;                // 64 KB
    float*    part  = (float*)(ws + 5832704);      // 768 KB (3 slots)
    float*    pz    = (float*)(ws + 6619136);      // 3 KB

    float* outRaw = (float*)d_out;
    float* node0  = outRaw + 512;
    float* node1  = node0 + 1048576;
    float* pool0  = node1 + 1048576;
    float* pool1  = pool0 + 512;

    k_setup<<<37760, 256, 0, stream>>>(adj, am, ge, in_w, in_b, xb,
                                       proj_w, ipw1, pw1, wT0, wT1, ipw1T, w1T0, w1T1);

    // L0 gemm_h + raw pool partials (both read initial xb)
    k_gemm_h_pool<<<512, 256, 0, stream>>>(xb, wT0, a_src, a_dst, hbT, srcM, dstT,
                                           ipw1T, ipb1, ipw2, ipb2, part, pz, 0);
    k_attn<<<dim3(64, 4, 2), 512, 0, stream>>>(srcM, dstT, am, hbT, node0, xb);

    // L1 gemm_h + pool(l0) partials (both read xb = node0 bf16)
    k_gemm_h_pool<<<512, 256, 0, stream>>>(xb, wT1, a_src + 256, a_dst + 256, hbT, srcM, dstT,
                                           w1T0, pb1, pw2, pb2, part, pz, 1);
    k_attn<<<dim3(64, 4, 2), 512, 0, stream>>>(srcM, dstT, am, hbT, node1, xb);

    // pool(l1) partials on xb = node1 bf16
    k_pool_sw<<<dim3(128, B_), 256, 0, stream>>>(xb, w1T1, pb1 + POOL_, pw2 + 1, pb2 + 1,
                                                 part, pz, 2);
    k_pool_finals<<<6, 256, 0, stream>>>(part, pz, outRaw, pool0, pool1);
}